// Round 2
// baseline (1088.365 us; speedup 1.0000x reference)
//
#include <hip/hip_runtime.h>
#include <hip/hip_bf16.h>

#define NUu 30000
#define NIi 15000
#define DD 64
#define RR 5
#define NU5 150000
#define NI5 75000
#define NADJ 105000
#define NNZ_S 1200000
#define NNZ_A 840000

#define SCAN_TPB 256
#define SCAN_ELEMS 8
#define SCAN_CHUNK (SCAN_TPB * SCAN_ELEMS)  // 2048

// ============================ CSR build ============================
__global__ void csr_count(const int* __restrict__ rows, int nnz, int* __restrict__ counts) {
    int e = blockIdx.x * blockDim.x + threadIdx.x;
    if (e < nnz) atomicAdd(&counts[rows[e]], 1);
}

// Block-local exclusive scan; writes partial ptr + per-block totals.
__global__ void scan_partial(const int* __restrict__ counts, int n,
                             int* __restrict__ ptr, int* __restrict__ blocksums) {
    __shared__ int sh[SCAN_TPB];
    int base = blockIdx.x * SCAN_CHUNK;
    int t = threadIdx.x;
    int loc[SCAN_ELEMS];
    int s = 0;
#pragma unroll
    for (int i = 0; i < SCAN_ELEMS; ++i) {
        int idx = base + t * SCAN_ELEMS + i;
        int v = (idx < n) ? counts[idx] : 0;
        loc[i] = s;  // thread-local exclusive prefix
        s += v;
    }
    sh[t] = s;
    __syncthreads();
    for (int off = 1; off < SCAN_TPB; off <<= 1) {
        int v = (t >= off) ? sh[t - off] : 0;
        __syncthreads();
        sh[t] += v;
        __syncthreads();
    }
    int texcl = (t == 0) ? 0 : sh[t - 1];
    if (t == SCAN_TPB - 1) blocksums[blockIdx.x] = sh[t];
#pragma unroll
    for (int i = 0; i < SCAN_ELEMS; ++i) {
        int idx = base + t * SCAN_ELEMS + i;
        if (idx < n) ptr[idx] = texcl + loc[i];
    }
}

// Single-block exclusive scan of block totals (nblocks <= 256).
__global__ void scan_blocksums(int* __restrict__ blocksums, int nblocks) {
    __shared__ int sh[SCAN_TPB];
    int t = threadIdx.x;
    int v = (t < nblocks) ? blocksums[t] : 0;
    sh[t] = v;
    __syncthreads();
    for (int off = 1; off < SCAN_TPB; off <<= 1) {
        int u = (t >= off) ? sh[t - off] : 0;
        __syncthreads();
        sh[t] += u;
        __syncthreads();
    }
    int excl = (t == 0) ? 0 : sh[t - 1];
    if (t < nblocks) blocksums[t] = excl;
}

__global__ void scan_add(int* __restrict__ ptr, int* __restrict__ cursor, int n, int nnz,
                         const int* __restrict__ blocksums) {
    int i = blockIdx.x * blockDim.x + threadIdx.x;
    if (i < n) {
        int v = ptr[i] + blocksums[i / SCAN_CHUNK];
        ptr[i] = v;
        cursor[i] = v;
    }
    if (i == 0) ptr[n] = nnz;
}

__global__ void csr_fill(const int* __restrict__ rows, const int* __restrict__ cols,
                         const float* __restrict__ vals, int nnz, int* __restrict__ cursor,
                         int* __restrict__ ecol, float* __restrict__ eval) {
    int e = blockIdx.x * blockDim.x + threadIdx.x;
    if (e >= nnz) return;
    int p = atomicAdd(&cursor[rows[e]], 1);
    ecol[p] = cols[e];
    eval[p] = vals[e];
}

// ============== SpMM (CSR gather): one wave per row, lane = component ==============
__global__ void spmm_csr(const int* __restrict__ ptr, const int* __restrict__ ecol,
                         const float* __restrict__ eval, const float* __restrict__ x,
                         float* __restrict__ out, int nrows) {
    int w = (blockIdx.x * blockDim.x + threadIdx.x) >> 6;
    int lane = threadIdx.x & 63;
    if (w >= nrows) return;
    int beg = ptr[w], end = ptr[w + 1];
    float acc = 0.f;
    int j = beg;
    for (; j + 1 < end; j += 2) {
        int c0 = ecol[j], c1 = ecol[j + 1];
        float v0 = eval[j], v1 = eval[j + 1];
        acc += v0 * x[(size_t)c0 * DD + lane];
        acc += v1 * x[(size_t)c1 * DD + lane];
    }
    if (j < end) acc += eval[j] * x[(size_t)ecol[j] * DD + lane];
    out[(size_t)w * DD + lane] = acc;
}

// ============== fallback: atomic SpMM (if ws too small for CSR) ==============
__global__ void spmm_atomic(const int* __restrict__ rows, const int* __restrict__ cols,
                            const float* __restrict__ vals, const float* __restrict__ x,
                            float* __restrict__ out, int nnz) {
    int tid = blockIdx.x * blockDim.x + threadIdx.x;
    int e = tid >> 4;
    if (e >= nnz) return;
    int lc = (tid & 15) << 2;
    int r = rows[e];
    int c = cols[e];
    float v = vals[e];
    const float4 xv = *reinterpret_cast<const float4*>(x + (size_t)c * DD + lc);
    float* o = out + (size_t)r * DD + lc;
    unsafeAtomicAdd(o + 0, v * xv.x);
    unsafeAtomicAdd(o + 1, v * xv.y);
    unsafeAtomicAdd(o + 2, v * xv.z);
    unsafeAtomicAdd(o + 3, v * xv.w);
}

// ============== dense fused kernels (one wave per row, weights in LDS) ==============
__global__ void gemm64_prelu(const float* __restrict__ X, const float* __restrict__ W,
                             const float* __restrict__ alpha_p, float* __restrict__ Y,
                             int nrows) {
    __shared__ float Ws[64 * 64];
    int t = threadIdx.x;
    for (int i = t; i < 64 * 64; i += 256) Ws[i] = W[i];
    __syncthreads();
    float alpha = alpha_p[0];
    int lane = t & 63;
    int row = blockIdx.x * 4 + (t >> 6);
    if (row >= nrows) return;
    float xv = X[(size_t)row * DD + lane];
    xv = xv >= 0.f ? xv : alpha * xv;
    float acc = 0.f;
#pragma unroll
    for (int k = 0; k < 64; ++k) acc += __shfl(xv, k, 64) * Ws[k * 64 + lane];
    Y[(size_t)row * DD + lane] = acc;
}

__global__ void fuse_u(const float* __restrict__ raw0, const float* __restrict__ raw1,
                       const float* __restrict__ w_r1_w, const float* __restrict__ w_r1_b,
                       const float* __restrict__ alpha_p, float* __restrict__ ego) {
    __shared__ float Wl[128 * 64];  // Wl[k][j] = w_r1_w[j][k]
    int t = threadIdx.x;
    for (int i = t; i < 64 * 128; i += 256) {
        int j = i >> 7, k = i & 127;
        Wl[k * 64 + j] = w_r1_w[i];
    }
    __syncthreads();
    float alpha = alpha_p[0];
    int lane = t & 63;
    int row = blockIdx.x * 4 + (t >> 6);
    if (row >= NUu) return;
    float s0 = 0.f, s1 = 0.f;
#pragma unroll
    for (int r = 0; r < RR; ++r) {
        float a = raw0[((size_t)row * RR + r) * DD + lane];
        s0 += (a >= 0.f ? a : alpha * a);
        float b = raw1[((size_t)row * RR + r) * DD + lane];
        s1 += (b >= 0.f ? b : alpha * b);
    }
    s0 *= 0.25f;
    s1 *= 0.25f;
    float acc = w_r1_b[lane];
#pragma unroll
    for (int k = 0; k < 64; ++k) {
        acc += __shfl(s0, k, 64) * Wl[k * 64 + lane];
        acc += __shfl(s1, k, 64) * Wl[(64 + k) * 64 + lane];
    }
    ego[(size_t)row * DD + lane] = acc;
}

__global__ void fuse_ego1(const float* __restrict__ embraw, const float* __restrict__ Wu,
                          const float* __restrict__ Wi, const float* __restrict__ alpha_p,
                          float* __restrict__ ego1) {
    __shared__ float Ws[2 * 64 * 64];
    int t = threadIdx.x;
    for (int i = t; i < 4096; i += 256) {
        Ws[i] = Wu[i];
        Ws[4096 + i] = Wi[i];
    }
    __syncthreads();
    float alpha = alpha_p[0];
    int lane = t & 63;
    int row = blockIdx.x * 4 + (t >> 6);
    if (row >= NADJ) return;
    const float* Wsel = (row < NUu) ? Ws : Ws + 4096;
    float xv = embraw[(size_t)row * DD + lane];
    xv = xv >= 0.f ? xv : alpha * xv;
    float acc = 0.f;
#pragma unroll
    for (int k = 0; k < 64; ++k) acc += __shfl(xv, k, 64) * Wsel[k * 64 + lane];
    ego1[(size_t)row * DD + lane] = acc;
}

__global__ void out_users(const float* __restrict__ embraw, const float* __restrict__ emb1raw,
                          const float* __restrict__ alpha_p, float* __restrict__ outp) {
    float alpha = alpha_p[0];
    int i = blockIdx.x * blockDim.x + threadIdx.x;
    if (i >= NUu * DD) return;
    int row = i >> 6, c = i & 63;
    float a = embraw[i];
    a = a >= 0.f ? a : alpha * a;
    float b = emb1raw[i];
    b = b >= 0.f ? b : alpha * b;
    outp[(size_t)row * 128 + c] = a;
    outp[(size_t)row * 128 + 64 + c] = b;
}

__global__ void out_items(const float* __restrict__ embraw, const float* __restrict__ emb1raw,
                          const float* __restrict__ alpha_p, float* __restrict__ outp) {
    float alpha = alpha_p[0];
    int i = blockIdx.x * blockDim.x + threadIdx.x;
    if (i >= NIi * DD) return;
    int row = i >> 6, c = i & 63;
    float s0 = 0.f, s1 = 0.f;
#pragma unroll
    for (int r = 0; r < RR; ++r) {
        size_t idx = ((size_t)NUu + (size_t)row * RR + r) * DD + c;
        float a = embraw[idx];
        s0 += (a >= 0.f ? a : alpha * a);
        float b = emb1raw[idx];
        s1 += (b >= 0.f ? b : alpha * b);
    }
    size_t obase = (size_t)NUu * 128 + (size_t)row * 128 + c;
    outp[obase] = s0 / 5.0f;
    outp[obase + 64] = s1 / 5.0f;
}

// ============================ host ============================
static void build_csr(const int* rows, const int* cols, const float* vals, int nnz, int nrows,
                      int* ptr, int* cur, int* ecol, float* eval, int* bsums,
                      hipStream_t stream) {
    hipMemsetAsync(cur, 0, (size_t)nrows * sizeof(int), stream);
    csr_count<<<(nnz + 255) / 256, 256, 0, stream>>>(rows, nnz, cur);
    int nblocks = (nrows + SCAN_CHUNK - 1) / SCAN_CHUNK;
    scan_partial<<<nblocks, SCAN_TPB, 0, stream>>>(cur, nrows, ptr, bsums);
    scan_blocksums<<<1, SCAN_TPB, 0, stream>>>(bsums, nblocks);
    scan_add<<<(nrows + 255) / 256, 256, 0, stream>>>(ptr, cur, nrows, nnz, bsums);
    csr_fill<<<(nnz + 255) / 256, 256, 0, stream>>>(rows, cols, vals, nnz, cur, ecol, eval);
}

extern "C" void kernel_launch(void* const* d_in, const int* in_sizes, int n_in,
                              void* d_out, int out_size, void* d_ws, size_t ws_size,
                              hipStream_t stream) {
    const float* user_emb  = (const float*)d_in[0];
    const float* item_emb  = (const float*)d_in[1];
    const float* w_r1_w    = (const float*)d_in[2];
    const float* w_r1_b    = (const float*)d_in[3];
    const float* social_w1 = (const float*)d_in[4];
    const float* user_w1   = (const float*)d_in[5];
    const float* item_w1   = (const float*)d_in[6];
    const float* alpha     = (const float*)d_in[7];
    const float* social_vals = (const float*)d_in[8];
    const float* adj_vals    = (const float*)d_in[9];
    const int* social_rows = (const int*)d_in[10];
    const int* social_cols = (const int*)d_in[11];
    const int* adj_rows    = (const int*)d_in[12];
    const int* adj_cols    = (const int*)d_in[13];
    float* out = (float*)d_out;

    // dense buffers
    float* A  = (float*)d_ws;              // raw0 -> ego1
    float* B  = A + (size_t)NU5 * DD;      // t1 -> ego
    float* C  = B + (size_t)NU5 * DD;      // raw1 -> emb1raw
    float* Dm = C + (size_t)NU5 * DD;      // embraw
    // CSR scratch
    int*   s_ptr = (int*)(Dm + (size_t)NADJ * DD);
    int*   s_cur = s_ptr + (NU5 + 1);
    int*   s_col = s_cur + NU5;
    float* s_val = (float*)(s_col + NNZ_S);
    int*   a_ptr = (int*)(s_val + NNZ_S);
    int*   a_cur = a_ptr + (NADJ + 1);
    int*   a_col = a_cur + NADJ;
    float* a_val = (float*)(a_col + NNZ_A);
    int*   bsums = (int*)(a_val + NNZ_A);
    size_t need = (size_t)((char*)(bsums + 128) - (char*)d_ws);

    if (ws_size >= need) {
        // ---- CSR path ----
        build_csr(social_rows, social_cols, social_vals, NNZ_S, NU5,
                  s_ptr, s_cur, s_col, s_val, bsums, stream);
        build_csr(adj_rows, adj_cols, adj_vals, NNZ_A, NADJ,
                  a_ptr, a_cur, a_col, a_val, bsums, stream);

        spmm_csr<<<(NU5 * 64 + 255) / 256, 256, 0, stream>>>(s_ptr, s_col, s_val, user_emb, A, NU5);
        gemm64_prelu<<<(NU5 + 3) / 4, 256, 0, stream>>>(A, social_w1, alpha, B, NU5);
        spmm_csr<<<(NU5 * 64 + 255) / 256, 256, 0, stream>>>(s_ptr, s_col, s_val, B, C, NU5);
        fuse_u<<<(NUu + 3) / 4, 256, 0, stream>>>(A, C, w_r1_w, w_r1_b, alpha, B);
        hipMemcpyAsync(B + (size_t)NUu * DD, item_emb, (size_t)NI5 * DD * sizeof(float),
                       hipMemcpyDeviceToDevice, stream);
        spmm_csr<<<(NADJ * 64 + 255) / 256, 256, 0, stream>>>(a_ptr, a_col, a_val, B, Dm, NADJ);
        fuse_ego1<<<(NADJ + 3) / 4, 256, 0, stream>>>(Dm, user_w1, item_w1, alpha, A);
        spmm_csr<<<(NADJ * 64 + 255) / 256, 256, 0, stream>>>(a_ptr, a_col, a_val, A, C, NADJ);
    } else {
        // ---- atomic fallback ----
        hipMemsetAsync(A, 0, (size_t)NU5 * DD * sizeof(float), stream);
        spmm_atomic<<<(NNZ_S * 16 + 255) / 256, 256, 0, stream>>>(
            social_rows, social_cols, social_vals, user_emb, A, NNZ_S);
        gemm64_prelu<<<(NU5 + 3) / 4, 256, 0, stream>>>(A, social_w1, alpha, B, NU5);
        hipMemsetAsync(C, 0, (size_t)NU5 * DD * sizeof(float), stream);
        spmm_atomic<<<(NNZ_S * 16 + 255) / 256, 256, 0, stream>>>(
            social_rows, social_cols, social_vals, B, C, NNZ_S);
        fuse_u<<<(NUu + 3) / 4, 256, 0, stream>>>(A, C, w_r1_w, w_r1_b, alpha, B);
        hipMemcpyAsync(B + (size_t)NUu * DD, item_emb, (size_t)NI5 * DD * sizeof(float),
                       hipMemcpyDeviceToDevice, stream);
        hipMemsetAsync(Dm, 0, (size_t)NADJ * DD * sizeof(float), stream);
        spmm_atomic<<<(NNZ_A * 16 + 255) / 256, 256, 0, stream>>>(
            adj_rows, adj_cols, adj_vals, B, Dm, NNZ_A);
        fuse_ego1<<<(NADJ + 3) / 4, 256, 0, stream>>>(Dm, user_w1, item_w1, alpha, A);
        hipMemsetAsync(C, 0, (size_t)NADJ * DD * sizeof(float), stream);
        spmm_atomic<<<(NNZ_A * 16 + 255) / 256, 256, 0, stream>>>(
            adj_rows, adj_cols, adj_vals, A, C, NNZ_A);
    }

    out_users<<<(NUu * DD + 255) / 256, 256, 0, stream>>>(Dm, C, alpha, out);
    out_items<<<(NIi * DD + 255) / 256, 256, 0, stream>>>(Dm, C, alpha, out);
}

// Round 3
// 902.074 us; speedup vs baseline: 1.2065x; 1.2065x over previous
//
#include <hip/hip_runtime.h>
#include <hip/hip_bf16.h>

#define NUu 30000
#define NIi 15000
#define DD 64
#define RR 5
#define NU5 150000
#define NI5 75000
#define NADJ 105000
#define NNZ_S 1200000
#define NNZ_A 840000

#define SCAN_TPB 256
#define SCAN_ELEMS 8
#define SCAN_CHUNK (SCAN_TPB * SCAN_ELEMS)  // 2048

// ============================ CSR build ============================
__global__ void csr_count(const int* __restrict__ rows, int nnz, int* __restrict__ counts) {
    int e = blockIdx.x * blockDim.x + threadIdx.x;
    if (e < nnz) atomicAdd(&counts[rows[e]], 1);
}

__global__ void scan_partial(const int* __restrict__ counts, int n,
                             int* __restrict__ ptr, int* __restrict__ blocksums) {
    __shared__ int sh[SCAN_TPB];
    int base = blockIdx.x * SCAN_CHUNK;
    int t = threadIdx.x;
    int loc[SCAN_ELEMS];
    int s = 0;
#pragma unroll
    for (int i = 0; i < SCAN_ELEMS; ++i) {
        int idx = base + t * SCAN_ELEMS + i;
        int v = (idx < n) ? counts[idx] : 0;
        loc[i] = s;
        s += v;
    }
    sh[t] = s;
    __syncthreads();
    for (int off = 1; off < SCAN_TPB; off <<= 1) {
        int v = (t >= off) ? sh[t - off] : 0;
        __syncthreads();
        sh[t] += v;
        __syncthreads();
    }
    int texcl = (t == 0) ? 0 : sh[t - 1];
    if (t == SCAN_TPB - 1) blocksums[blockIdx.x] = sh[t];
#pragma unroll
    for (int i = 0; i < SCAN_ELEMS; ++i) {
        int idx = base + t * SCAN_ELEMS + i;
        if (idx < n) ptr[idx] = texcl + loc[i];
    }
}

__global__ void scan_blocksums(int* __restrict__ blocksums, int nblocks) {
    __shared__ int sh[SCAN_TPB];
    int t = threadIdx.x;
    int v = (t < nblocks) ? blocksums[t] : 0;
    sh[t] = v;
    __syncthreads();
    for (int off = 1; off < SCAN_TPB; off <<= 1) {
        int u = (t >= off) ? sh[t - off] : 0;
        __syncthreads();
        sh[t] += u;
        __syncthreads();
    }
    int excl = (t == 0) ? 0 : sh[t - 1];
    if (t < nblocks) blocksums[t] = excl;
}

__global__ void scan_add(int* __restrict__ ptr, int* __restrict__ cursor, int n, int nnz,
                         const int* __restrict__ blocksums) {
    int i = blockIdx.x * blockDim.x + threadIdx.x;
    if (i < n) {
        int v = ptr[i] + blocksums[i / SCAN_CHUNK];
        ptr[i] = v;
        cursor[i] = v;
    }
    if (i == 0) ptr[n] = nnz;
}

__global__ void csr_fill(const int* __restrict__ rows, const int* __restrict__ cols,
                         const float* __restrict__ vals, int nnz, int* __restrict__ cursor,
                         int2* __restrict__ ecv) {
    int e = blockIdx.x * blockDim.x + threadIdx.x;
    if (e >= nnz) return;
    int p = atomicAdd(&cursor[rows[e]], 1);
    ecv[p] = make_int2(cols[e], __float_as_int(vals[e]));
}

// ============== SpMM (CSR gather): one wave per row, lane = component ==============
template <bool SPLIT>
__global__ void spmm_csr(const int* __restrict__ ptr, const int2* __restrict__ ecv,
                         const float* __restrict__ x, const float* __restrict__ x2,
                         float* __restrict__ out, int nrows) {
    int w = (blockIdx.x * blockDim.x + threadIdx.x) >> 6;
    int lane = threadIdx.x & 63;
    if (w >= nrows) return;
    int beg = ptr[w], end = ptr[w + 1];
    float a0 = 0.f, a1 = 0.f, a2 = 0.f, a3 = 0.f;
    int j = beg;
    for (; j + 3 < end; j += 4) {
        int2 e0 = ecv[j], e1 = ecv[j + 1], e2 = ecv[j + 2], e3 = ecv[j + 3];
        const float *p0, *p1, *p2, *p3;
        if (SPLIT) {
            p0 = (e0.x < NUu) ? x + (size_t)e0.x * DD : x2 + (size_t)(e0.x - NUu) * DD;
            p1 = (e1.x < NUu) ? x + (size_t)e1.x * DD : x2 + (size_t)(e1.x - NUu) * DD;
            p2 = (e2.x < NUu) ? x + (size_t)e2.x * DD : x2 + (size_t)(e2.x - NUu) * DD;
            p3 = (e3.x < NUu) ? x + (size_t)e3.x * DD : x2 + (size_t)(e3.x - NUu) * DD;
        } else {
            p0 = x + (size_t)e0.x * DD;
            p1 = x + (size_t)e1.x * DD;
            p2 = x + (size_t)e2.x * DD;
            p3 = x + (size_t)e3.x * DD;
        }
        a0 += __int_as_float(e0.y) * p0[lane];
        a1 += __int_as_float(e1.y) * p1[lane];
        a2 += __int_as_float(e2.y) * p2[lane];
        a3 += __int_as_float(e3.y) * p3[lane];
    }
    for (; j < end; ++j) {
        int2 e0 = ecv[j];
        const float* p0;
        if (SPLIT)
            p0 = (e0.x < NUu) ? x + (size_t)e0.x * DD : x2 + (size_t)(e0.x - NUu) * DD;
        else
            p0 = x + (size_t)e0.x * DD;
        a0 += __int_as_float(e0.y) * p0[lane];
    }
    out[(size_t)w * DD + lane] = (a0 + a1) + (a2 + a3);
}

// ============== fallback: atomic SpMM (if ws too small for CSR) ==============
__global__ void spmm_atomic(const int* __restrict__ rows, const int* __restrict__ cols,
                            const float* __restrict__ vals, const float* __restrict__ x,
                            float* __restrict__ out, int nnz) {
    int tid = blockIdx.x * blockDim.x + threadIdx.x;
    int e = tid >> 4;
    if (e >= nnz) return;
    int lc = (tid & 15) << 2;
    int r = rows[e];
    int c = cols[e];
    float v = vals[e];
    const float4 xv = *reinterpret_cast<const float4*>(x + (size_t)c * DD + lc);
    float* o = out + (size_t)r * DD + lc;
    unsafeAtomicAdd(o + 0, v * xv.x);
    unsafeAtomicAdd(o + 1, v * xv.y);
    unsafeAtomicAdd(o + 2, v * xv.z);
    unsafeAtomicAdd(o + 3, v * xv.w);
}

// ============== dense fused kernels (persistent, one wave per row-iter) ==============
__global__ void gemm64_prelu(const float* __restrict__ X, const float* __restrict__ W,
                             const float* __restrict__ alpha_p, float* __restrict__ Y,
                             int nrows) {
    __shared__ float Ws[64 * 64];
    int t = threadIdx.x;
    for (int i = t; i < 64 * 64; i += 256) Ws[i] = W[i];
    __syncthreads();
    float alpha = alpha_p[0];
    int lane = t & 63;
    int gw = (blockIdx.x * 256 + t) >> 6;
    int nw = gridDim.x * 4;
    for (int row = gw; row < nrows; row += nw) {
        float xv = X[(size_t)row * DD + lane];
        xv = xv >= 0.f ? xv : alpha * xv;
        float acc = 0.f;
#pragma unroll
        for (int k = 0; k < 64; ++k) acc += __shfl(xv, k, 64) * Ws[k * 64 + lane];
        Y[(size_t)row * DD + lane] = acc;
    }
}

// u = (sum_r prelu(raw0)/4 | sum_r prelu(raw1)/4) @ w_r1_w.T + b  -> uout[0:NU*D]
__global__ void fuse_u(const float* __restrict__ raw0, const float* __restrict__ raw1,
                       const float* __restrict__ w_r1_w, const float* __restrict__ w_r1_b,
                       const float* __restrict__ alpha_p, float* __restrict__ uout) {
    __shared__ float Wl[128 * 65];  // Wl[k*65+j] = w_r1_w[j][k]; pad 65 kills write conflicts
    int t = threadIdx.x;
    for (int i = t; i < 64 * 128; i += 256) {
        int j = i >> 7, k = i & 127;
        Wl[k * 65 + j] = w_r1_w[i];
    }
    __syncthreads();
    float alpha = alpha_p[0];
    int lane = t & 63;
    int gw = (blockIdx.x * 256 + t) >> 6;
    int nw = gridDim.x * 4;
    for (int row = gw; row < NUu; row += nw) {
        float s0 = 0.f, s1 = 0.f;
#pragma unroll
        for (int r = 0; r < RR; ++r) {
            float a = raw0[((size_t)row * RR + r) * DD + lane];
            s0 += (a >= 0.f ? a : alpha * a);
            float b = raw1[((size_t)row * RR + r) * DD + lane];
            s1 += (b >= 0.f ? b : alpha * b);
        }
        s0 *= 0.25f;
        s1 *= 0.25f;
        float acc = w_r1_b[lane];
#pragma unroll
        for (int k = 0; k < 64; ++k) {
            acc += __shfl(s0, k, 64) * Wl[k * 65 + lane];
            acc += __shfl(s1, k, 64) * Wl[(64 + k) * 65 + lane];
        }
        uout[(size_t)row * DD + lane] = acc;
    }
}

__global__ void fuse_ego1(const float* __restrict__ embraw, const float* __restrict__ Wu,
                          const float* __restrict__ Wi, const float* __restrict__ alpha_p,
                          float* __restrict__ ego1) {
    __shared__ float Ws[2 * 64 * 64];
    int t = threadIdx.x;
    for (int i = t; i < 4096; i += 256) {
        Ws[i] = Wu[i];
        Ws[4096 + i] = Wi[i];
    }
    __syncthreads();
    float alpha = alpha_p[0];
    int lane = t & 63;
    int gw = (blockIdx.x * 256 + t) >> 6;
    int nw = gridDim.x * 4;
    for (int row = gw; row < NADJ; row += nw) {
        const float* Wsel = (row < NUu) ? Ws : Ws + 4096;
        float xv = embraw[(size_t)row * DD + lane];
        xv = xv >= 0.f ? xv : alpha * xv;
        float acc = 0.f;
#pragma unroll
        for (int k = 0; k < 64; ++k) acc += __shfl(xv, k, 64) * Wsel[k * 64 + lane];
        ego1[(size_t)row * DD + lane] = acc;
    }
}

// ============== outputs (users + items in one kernel) ==============
__global__ void out_combined(const float* __restrict__ embraw, const float* __restrict__ emb1raw,
                             const float* __restrict__ alpha_p, float* __restrict__ outp) {
    float alpha = alpha_p[0];
    int i = blockIdx.x * blockDim.x + threadIdx.x;
    if (i < NUu * DD) {
        int row = i >> 6, c = i & 63;
        float a = embraw[i];
        a = a >= 0.f ? a : alpha * a;
        float b = emb1raw[i];
        b = b >= 0.f ? b : alpha * b;
        outp[(size_t)row * 128 + c] = a;
        outp[(size_t)row * 128 + 64 + c] = b;
    } else {
        int i2 = i - NUu * DD;
        if (i2 >= NIi * DD) return;
        int row = i2 >> 6, c = i2 & 63;
        float s0 = 0.f, s1 = 0.f;
#pragma unroll
        for (int r = 0; r < RR; ++r) {
            size_t idx = ((size_t)NUu + (size_t)row * RR + r) * DD + c;
            float a = embraw[idx];
            s0 += (a >= 0.f ? a : alpha * a);
            float b = emb1raw[idx];
            s1 += (b >= 0.f ? b : alpha * b);
        }
        size_t obase = (size_t)NUu * 128 + (size_t)row * 128 + c;
        outp[obase] = s0 / 5.0f;
        outp[obase + 64] = s1 / 5.0f;
    }
}

// ============================ host ============================
static void build_csr(const int* rows, const int* cols, const float* vals, int nnz, int nrows,
                      int* ptr, int* cur, int2* ecv, int* bsums, hipStream_t stream) {
    hipMemsetAsync(cur, 0, (size_t)nrows * sizeof(int), stream);
    csr_count<<<(nnz + 255) / 256, 256, 0, stream>>>(rows, nnz, cur);
    int nblocks = (nrows + SCAN_CHUNK - 1) / SCAN_CHUNK;
    scan_partial<<<nblocks, SCAN_TPB, 0, stream>>>(cur, nrows, ptr, bsums);
    scan_blocksums<<<1, SCAN_TPB, 0, stream>>>(bsums, nblocks);
    scan_add<<<(nrows + 255) / 256, 256, 0, stream>>>(ptr, cur, nrows, nnz, bsums);
    csr_fill<<<(nnz + 255) / 256, 256, 0, stream>>>(rows, cols, vals, nnz, cur, ecv);
}

extern "C" void kernel_launch(void* const* d_in, const int* in_sizes, int n_in,
                              void* d_out, int out_size, void* d_ws, size_t ws_size,
                              hipStream_t stream) {
    const float* user_emb  = (const float*)d_in[0];
    const float* item_emb  = (const float*)d_in[1];
    const float* w_r1_w    = (const float*)d_in[2];
    const float* w_r1_b    = (const float*)d_in[3];
    const float* social_w1 = (const float*)d_in[4];
    const float* user_w1   = (const float*)d_in[5];
    const float* item_w1   = (const float*)d_in[6];
    const float* alpha     = (const float*)d_in[7];
    const float* social_vals = (const float*)d_in[8];
    const float* adj_vals    = (const float*)d_in[9];
    const int* social_rows = (const int*)d_in[10];
    const int* social_cols = (const int*)d_in[11];
    const int* adj_rows    = (const int*)d_in[12];
    const int* adj_cols    = (const int*)d_in[13];
    float* out = (float*)d_out;

    // dense buffers
    float* A  = (float*)d_ws;              // raw0 -> ego1
    float* B  = A + (size_t)NU5 * DD;      // t1 -> u
    float* C  = B + (size_t)NU5 * DD;      // raw1 -> emb1raw
    float* Dm = C + (size_t)NU5 * DD;      // embraw
    // CSR scratch (keep int2 regions 8B-aligned: pad ptr arrays to even counts)
    int*  s_ptr = (int*)(Dm + (size_t)NADJ * DD);
    int*  s_cur = s_ptr + (NU5 + 2);
    int2* s_ecv = (int2*)(s_cur + NU5);
    int*  a_ptr = (int*)(s_ecv + NNZ_S);
    int*  a_cur = a_ptr + (NADJ + 2);
    int2* a_ecv = (int2*)(a_cur + NADJ);
    int*  bsums = (int*)(a_ecv + NNZ_A);
    size_t need = (size_t)((char*)(bsums + 128) - (char*)d_ws);

    if (ws_size >= need) {
        build_csr(social_rows, social_cols, social_vals, NNZ_S, NU5,
                  s_ptr, s_cur, s_ecv, bsums, stream);
        build_csr(adj_rows, adj_cols, adj_vals, NNZ_A, NADJ,
                  a_ptr, a_cur, a_ecv, bsums, stream);

        // raw0 = S @ user_emb -> A
        spmm_csr<false><<<(NU5 * 64 + 255) / 256, 256, 0, stream>>>(
            s_ptr, s_ecv, user_emb, nullptr, A, NU5);
        // t1 = prelu(raw0) @ social_w1 -> B
        gemm64_prelu<<<1024, 256, 0, stream>>>(A, social_w1, alpha, B, NU5);
        // raw1 = S @ t1 -> C
        spmm_csr<false><<<(NU5 * 64 + 255) / 256, 256, 0, stream>>>(
            s_ptr, s_ecv, B, nullptr, C, NU5);
        // u -> B[0:NU*D]
        fuse_u<<<1024, 256, 0, stream>>>(A, C, w_r1_w, w_r1_b, alpha, B);
        // embraw = Adj @ [u ; item_emb] -> Dm  (virtual concat, no memcpy)
        spmm_csr<true><<<(NADJ * 64 + 255) / 256, 256, 0, stream>>>(
            a_ptr, a_ecv, B, item_emb, Dm, NADJ);
        // ego1 = prelu(embraw) @ {user_w1|item_w1} -> A
        fuse_ego1<<<1024, 256, 0, stream>>>(Dm, user_w1, item_w1, alpha, A);
        // emb1raw = Adj @ ego1 -> C
        spmm_csr<false><<<(NADJ * 64 + 255) / 256, 256, 0, stream>>>(
            a_ptr, a_ecv, A, nullptr, C, NADJ);
    } else {
        // ---- atomic fallback ----
        hipMemsetAsync(A, 0, (size_t)NU5 * DD * sizeof(float), stream);
        spmm_atomic<<<(NNZ_S * 16 + 255) / 256, 256, 0, stream>>>(
            social_rows, social_cols, social_vals, user_emb, A, NNZ_S);
        gemm64_prelu<<<1024, 256, 0, stream>>>(A, social_w1, alpha, B, NU5);
        hipMemsetAsync(C, 0, (size_t)NU5 * DD * sizeof(float), stream);
        spmm_atomic<<<(NNZ_S * 16 + 255) / 256, 256, 0, stream>>>(
            social_rows, social_cols, social_vals, B, C, NNZ_S);
        fuse_u<<<1024, 256, 0, stream>>>(A, C, w_r1_w, w_r1_b, alpha, B);
        hipMemcpyAsync(B + (size_t)NUu * DD, item_emb, (size_t)NI5 * DD * sizeof(float),
                       hipMemcpyDeviceToDevice, stream);
        hipMemsetAsync(Dm, 0, (size_t)NADJ * DD * sizeof(float), stream);
        spmm_atomic<<<(NNZ_A * 16 + 255) / 256, 256, 0, stream>>>(
            adj_rows, adj_cols, adj_vals, B, Dm, NNZ_A);
        fuse_ego1<<<1024, 256, 0, stream>>>(Dm, user_w1, item_w1, alpha, A);
        hipMemsetAsync(C, 0, (size_t)NADJ * DD * sizeof(float), stream);
        spmm_atomic<<<(NNZ_A * 16 + 255) / 256, 256, 0, stream>>>(
            adj_rows, adj_cols, adj_vals, A, C, NNZ_A);
    }

    out_combined<<<((NUu + NIi) * DD + 255) / 256, 256, 0, stream>>>(Dm, C, alpha, out);
}

// Round 4
// 739.192 us; speedup vs baseline: 1.4724x; 1.2204x over previous
//
#include <hip/hip_runtime.h>
#include <hip/hip_bf16.h>

#define NUu 30000
#define NIi 15000
#define DD 64
#define RR 5
#define NU5 150000
#define NI5 75000
#define NADJ 105000
#define NNZ_S 1200000
#define NNZ_A 840000

#define SCAN_TPB 256
#define SCAN_ELEMS 8
#define SCAN_CHUNK (SCAN_TPB * SCAN_ELEMS)  // 2048

// ============================ CSR build ============================
__global__ void csr_count(const int* __restrict__ rows, int nnz, int* __restrict__ counts) {
    int e = blockIdx.x * blockDim.x + threadIdx.x;
    if (e < nnz) atomicAdd(&counts[rows[e]], 1);
}

__global__ void scan_partial(const int* __restrict__ counts, int n,
                             int* __restrict__ ptr, int* __restrict__ blocksums) {
    __shared__ int sh[SCAN_TPB];
    int base = blockIdx.x * SCAN_CHUNK;
    int t = threadIdx.x;
    int loc[SCAN_ELEMS];
    int s = 0;
#pragma unroll
    for (int i = 0; i < SCAN_ELEMS; ++i) {
        int idx = base + t * SCAN_ELEMS + i;
        int v = (idx < n) ? counts[idx] : 0;
        loc[i] = s;
        s += v;
    }
    sh[t] = s;
    __syncthreads();
    for (int off = 1; off < SCAN_TPB; off <<= 1) {
        int v = (t >= off) ? sh[t - off] : 0;
        __syncthreads();
        sh[t] += v;
        __syncthreads();
    }
    int texcl = (t == 0) ? 0 : sh[t - 1];
    if (t == SCAN_TPB - 1) blocksums[blockIdx.x] = sh[t];
#pragma unroll
    for (int i = 0; i < SCAN_ELEMS; ++i) {
        int idx = base + t * SCAN_ELEMS + i;
        if (idx < n) ptr[idx] = texcl + loc[i];
    }
}

__global__ void scan_blocksums(int* __restrict__ blocksums, int nblocks) {
    __shared__ int sh[SCAN_TPB];
    int t = threadIdx.x;
    int v = (t < nblocks) ? blocksums[t] : 0;
    sh[t] = v;
    __syncthreads();
    for (int off = 1; off < SCAN_TPB; off <<= 1) {
        int u = (t >= off) ? sh[t - off] : 0;
        __syncthreads();
        sh[t] += u;
        __syncthreads();
    }
    int excl = (t == 0) ? 0 : sh[t - 1];
    if (t < nblocks) blocksums[t] = excl;
}

__global__ void scan_add(int* __restrict__ ptr, int* __restrict__ cursor, int n, int nnz,
                         const int* __restrict__ blocksums) {
    int i = blockIdx.x * blockDim.x + threadIdx.x;
    if (i < n) {
        int v = ptr[i] + blocksums[i / SCAN_CHUNK];
        ptr[i] = v;
        cursor[i] = v;
    }
    if (i == 0) ptr[n] = nnz;
}

__global__ void csr_fill(const int* __restrict__ rows, const int* __restrict__ cols,
                         const float* __restrict__ vals, int nnz, int* __restrict__ cursor,
                         int2* __restrict__ ecv) {
    int e = blockIdx.x * blockDim.x + threadIdx.x;
    if (e >= nnz) return;
    int p = atomicAdd(&cursor[rows[e]], 1);
    ecv[p] = make_int2(cols[e], __float_as_int(vals[e]));
}

// ============== SpMM (CSR gather): one wave per row, lane = component ==============
template <bool SPLIT>
__global__ void spmm_csr(const int* __restrict__ ptr, const int2* __restrict__ ecv,
                         const float* __restrict__ x, const float* __restrict__ x2,
                         float* __restrict__ out, int nrows) {
    int w = (blockIdx.x * blockDim.x + threadIdx.x) >> 6;
    int lane = threadIdx.x & 63;
    if (w >= nrows) return;
    int beg = ptr[w], end = ptr[w + 1];
    float a0 = 0.f, a1 = 0.f, a2 = 0.f, a3 = 0.f;
    int j = beg;
    for (; j + 3 < end; j += 4) {
        int2 e0 = ecv[j], e1 = ecv[j + 1], e2 = ecv[j + 2], e3 = ecv[j + 3];
        const float *p0, *p1, *p2, *p3;
        if (SPLIT) {
            p0 = (e0.x < NUu) ? x + (size_t)e0.x * DD : x2 + (size_t)(e0.x - NUu) * DD;
            p1 = (e1.x < NUu) ? x + (size_t)e1.x * DD : x2 + (size_t)(e1.x - NUu) * DD;
            p2 = (e2.x < NUu) ? x + (size_t)e2.x * DD : x2 + (size_t)(e2.x - NUu) * DD;
            p3 = (e3.x < NUu) ? x + (size_t)e3.x * DD : x2 + (size_t)(e3.x - NUu) * DD;
        } else {
            p0 = x + (size_t)e0.x * DD;
            p1 = x + (size_t)e1.x * DD;
            p2 = x + (size_t)e2.x * DD;
            p3 = x + (size_t)e3.x * DD;
        }
        a0 += __int_as_float(e0.y) * p0[lane];
        a1 += __int_as_float(e1.y) * p1[lane];
        a2 += __int_as_float(e2.y) * p2[lane];
        a3 += __int_as_float(e3.y) * p3[lane];
    }
    for (; j < end; ++j) {
        int2 e0 = ecv[j];
        const float* p0;
        if (SPLIT)
            p0 = (e0.x < NUu) ? x + (size_t)e0.x * DD : x2 + (size_t)(e0.x - NUu) * DD;
        else
            p0 = x + (size_t)e0.x * DD;
        a0 += __int_as_float(e0.y) * p0[lane];
    }
    out[(size_t)w * DD + lane] = (a0 + a1) + (a2 + a3);
}

// ============== fallback: atomic SpMM (if ws too small for CSR) ==============
__global__ void spmm_atomic(const int* __restrict__ rows, const int* __restrict__ cols,
                            const float* __restrict__ vals, const float* __restrict__ x,
                            float* __restrict__ out, int nnz) {
    int tid = blockIdx.x * blockDim.x + threadIdx.x;
    int e = tid >> 4;
    if (e >= nnz) return;
    int lc = (tid & 15) << 2;
    int r = rows[e];
    int c = cols[e];
    float v = vals[e];
    const float4 xv = *reinterpret_cast<const float4*>(x + (size_t)c * DD + lc);
    float* o = out + (size_t)r * DD + lc;
    unsafeAtomicAdd(o + 0, v * xv.x);
    unsafeAtomicAdd(o + 1, v * xv.y);
    unsafeAtomicAdd(o + 2, v * xv.z);
    unsafeAtomicAdd(o + 3, v * xv.w);
}

// ============== dense kernels: row-per-thread, W broadcast from LDS ==============
#define PRELU(v) ((v) >= 0.f ? (v) : alpha * (v))

// Y[row] = prelu(X[row]) @ W   (64 rows/block, thread owns a row, 16 cols)
__global__ void gemm64_prelu(const float* __restrict__ X, const float* __restrict__ W,
                             const float* __restrict__ alpha_p, float* __restrict__ Y,
                             int nrows) {
    __shared__ float4 Ws[64 * 16];  // Ws[k*16 + c4] = W[k][4*c4 .. 4*c4+3]
    int t = threadIdx.x;
    {
        const float4* Wv = (const float4*)W;
        for (int i = t; i < 1024; i += 256) Ws[i] = Wv[i];
    }
    __syncthreads();
    float alpha = alpha_p[0];
    int lane = t & 63;
    int g = t >> 6;          // col group: cols g*16 .. g*16+15
    int row = blockIdx.x * 64 + lane;
    if (row >= nrows) return;

    float xr[64];
    const float4* xp = (const float4*)(X + (size_t)row * DD);
#pragma unroll
    for (int i = 0; i < 16; ++i) {
        float4 v = xp[i];
        xr[4 * i + 0] = PRELU(v.x);
        xr[4 * i + 1] = PRELU(v.y);
        xr[4 * i + 2] = PRELU(v.z);
        xr[4 * i + 3] = PRELU(v.w);
    }
    float4 a0 = {0, 0, 0, 0}, a1 = a0, a2 = a0, a3 = a0;
#pragma unroll
    for (int k = 0; k < 64; ++k) {
        float xk = xr[k];
        const float4* wr = &Ws[k * 16 + g * 4];
        float4 w0 = wr[0], w1 = wr[1], w2 = wr[2], w3 = wr[3];
        a0.x += xk * w0.x; a0.y += xk * w0.y; a0.z += xk * w0.z; a0.w += xk * w0.w;
        a1.x += xk * w1.x; a1.y += xk * w1.y; a1.z += xk * w1.z; a1.w += xk * w1.w;
        a2.x += xk * w2.x; a2.y += xk * w2.y; a2.z += xk * w2.z; a2.w += xk * w2.w;
        a3.x += xk * w3.x; a3.y += xk * w3.y; a3.z += xk * w3.z; a3.w += xk * w3.w;
    }
    float4* yp = (float4*)(Y + (size_t)row * DD + g * 16);
    yp[0] = a0; yp[1] = a1; yp[2] = a2; yp[3] = a3;
}

// u = (sum_r prelu(raw0)/4 || sum_r prelu(raw1)/4) @ w_r1_w.T + b  -> uout[0:NU*D]
__global__ void fuse_u(const float* __restrict__ raw0, const float* __restrict__ raw1,
                       const float* __restrict__ w_r1_w, const float* __restrict__ w_r1_b,
                       const float* __restrict__ alpha_p, float* __restrict__ uout) {
    __shared__ float Wl[128 * 68];  // Wl[k*68+j] = w_r1_w[j][k]; stride 68 keeps float4 align
    int t = threadIdx.x;
    for (int i = t; i < 8192; i += 256) {
        int j = i >> 7, k = i & 127;
        Wl[k * 68 + j] = w_r1_w[i];
    }
    __syncthreads();
    float alpha = alpha_p[0];
    int lane = t & 63;
    int g = t >> 6;
    int row = blockIdx.x * 64 + lane;
    if (row >= NUu) return;

    const float4* bp = (const float4*)(w_r1_b + g * 16);
    float4 a0 = bp[0], a1 = bp[1], a2 = bp[2], a3 = bp[3];
    float xr[64];

    // phase A: s0 from raw0 (5 replicas, contiguous per row)
    const float4* rp = (const float4*)(raw0 + (size_t)row * RR * DD);
#pragma unroll
    for (int i = 0; i < 16; ++i) {
        float sx = 0.f, sy = 0.f, sz = 0.f, sw = 0.f;
#pragma unroll
        for (int r = 0; r < RR; ++r) {
            float4 v = rp[r * 16 + i];
            sx += PRELU(v.x); sy += PRELU(v.y); sz += PRELU(v.z); sw += PRELU(v.w);
        }
        xr[4 * i + 0] = sx * 0.25f;
        xr[4 * i + 1] = sy * 0.25f;
        xr[4 * i + 2] = sz * 0.25f;
        xr[4 * i + 3] = sw * 0.25f;
    }
#pragma unroll
    for (int k = 0; k < 64; ++k) {
        float xk = xr[k];
        const float4* wr = (const float4*)(Wl + k * 68 + g * 16);
        float4 w0 = wr[0], w1 = wr[1], w2 = wr[2], w3 = wr[3];
        a0.x += xk * w0.x; a0.y += xk * w0.y; a0.z += xk * w0.z; a0.w += xk * w0.w;
        a1.x += xk * w1.x; a1.y += xk * w1.y; a1.z += xk * w1.z; a1.w += xk * w1.w;
        a2.x += xk * w2.x; a2.y += xk * w2.y; a2.z += xk * w2.z; a2.w += xk * w2.w;
        a3.x += xk * w3.x; a3.y += xk * w3.y; a3.z += xk * w3.z; a3.w += xk * w3.w;
    }
    // phase B: s1 from raw1
    rp = (const float4*)(raw1 + (size_t)row * RR * DD);
#pragma unroll
    for (int i = 0; i < 16; ++i) {
        float sx = 0.f, sy = 0.f, sz = 0.f, sw = 0.f;
#pragma unroll
        for (int r = 0; r < RR; ++r) {
            float4 v = rp[r * 16 + i];
            sx += PRELU(v.x); sy += PRELU(v.y); sz += PRELU(v.z); sw += PRELU(v.w);
        }
        xr[4 * i + 0] = sx * 0.25f;
        xr[4 * i + 1] = sy * 0.25f;
        xr[4 * i + 2] = sz * 0.25f;
        xr[4 * i + 3] = sw * 0.25f;
    }
#pragma unroll
    for (int k = 0; k < 64; ++k) {
        float xk = xr[k];
        const float4* wr = (const float4*)(Wl + (64 + k) * 68 + g * 16);
        float4 w0 = wr[0], w1 = wr[1], w2 = wr[2], w3 = wr[3];
        a0.x += xk * w0.x; a0.y += xk * w0.y; a0.z += xk * w0.z; a0.w += xk * w0.w;
        a1.x += xk * w1.x; a1.y += xk * w1.y; a1.z += xk * w1.z; a1.w += xk * w1.w;
        a2.x += xk * w2.x; a2.y += xk * w2.y; a2.z += xk * w2.z; a2.w += xk * w2.w;
        a3.x += xk * w3.x; a3.y += xk * w3.y; a3.z += xk * w3.z; a3.w += xk * w3.w;
    }
    float4* yp = (float4*)(uout + (size_t)row * DD + g * 16);
    yp[0] = a0; yp[1] = a1; yp[2] = a2; yp[3] = a3;
}

// ego1[row] = prelu(embraw[row]) @ (row<NU ? Wu : Wi)
__global__ void fuse_ego1(const float* __restrict__ embraw, const float* __restrict__ Wu,
                          const float* __restrict__ Wi, const float* __restrict__ alpha_p,
                          float* __restrict__ ego1) {
    __shared__ float4 Ws[2 * 64 * 16];
    int t = threadIdx.x;
    {
        const float4* Wv = (const float4*)Wu;
        const float4* Wv2 = (const float4*)Wi;
        for (int i = t; i < 1024; i += 256) {
            Ws[i] = Wv[i];
            Ws[1024 + i] = Wv2[i];
        }
    }
    __syncthreads();
    float alpha = alpha_p[0];
    int lane = t & 63;
    int g = t >> 6;
    int row = blockIdx.x * 64 + lane;
    if (row >= NADJ) return;
    const float4* Wb = (row < NUu) ? Ws : Ws + 1024;

    float xr[64];
    const float4* xp = (const float4*)(embraw + (size_t)row * DD);
#pragma unroll
    for (int i = 0; i < 16; ++i) {
        float4 v = xp[i];
        xr[4 * i + 0] = PRELU(v.x);
        xr[4 * i + 1] = PRELU(v.y);
        xr[4 * i + 2] = PRELU(v.z);
        xr[4 * i + 3] = PRELU(v.w);
    }
    float4 a0 = {0, 0, 0, 0}, a1 = a0, a2 = a0, a3 = a0;
#pragma unroll
    for (int k = 0; k < 64; ++k) {
        float xk = xr[k];
        const float4* wr = &Wb[k * 16 + g * 4];
        float4 w0 = wr[0], w1 = wr[1], w2 = wr[2], w3 = wr[3];
        a0.x += xk * w0.x; a0.y += xk * w0.y; a0.z += xk * w0.z; a0.w += xk * w0.w;
        a1.x += xk * w1.x; a1.y += xk * w1.y; a1.z += xk * w1.z; a1.w += xk * w1.w;
        a2.x += xk * w2.x; a2.y += xk * w2.y; a2.z += xk * w2.z; a2.w += xk * w2.w;
        a3.x += xk * w3.x; a3.y += xk * w3.y; a3.z += xk * w3.z; a3.w += xk * w3.w;
    }
    float4* yp = (float4*)(ego1 + (size_t)row * DD + g * 16);
    yp[0] = a0; yp[1] = a1; yp[2] = a2; yp[3] = a3;
}

// ============== outputs (users + items in one kernel) ==============
__global__ void out_combined(const float* __restrict__ embraw, const float* __restrict__ emb1raw,
                             const float* __restrict__ alpha_p, float* __restrict__ outp) {
    float alpha = alpha_p[0];
    int i = blockIdx.x * blockDim.x + threadIdx.x;
    if (i < NUu * DD) {
        int row = i >> 6, c = i & 63;
        float a = embraw[i];
        a = PRELU(a);
        float b = emb1raw[i];
        b = PRELU(b);
        outp[(size_t)row * 128 + c] = a;
        outp[(size_t)row * 128 + 64 + c] = b;
    } else {
        int i2 = i - NUu * DD;
        if (i2 >= NIi * DD) return;
        int row = i2 >> 6, c = i2 & 63;
        float s0 = 0.f, s1 = 0.f;
#pragma unroll
        for (int r = 0; r < RR; ++r) {
            size_t idx = ((size_t)NUu + (size_t)row * RR + r) * DD + c;
            float a = embraw[idx];
            s0 += PRELU(a);
            float b = emb1raw[idx];
            s1 += PRELU(b);
        }
        size_t obase = (size_t)NUu * 128 + (size_t)row * 128 + c;
        outp[obase] = s0 / 5.0f;
        outp[obase + 64] = s1 / 5.0f;
    }
}

// ============================ host ============================
static void build_csr(const int* rows, const int* cols, const float* vals, int nnz, int nrows,
                      int* ptr, int* cur, int2* ecv, int* bsums, hipStream_t stream) {
    hipMemsetAsync(cur, 0, (size_t)nrows * sizeof(int), stream);
    csr_count<<<(nnz + 255) / 256, 256, 0, stream>>>(rows, nnz, cur);
    int nblocks = (nrows + SCAN_CHUNK - 1) / SCAN_CHUNK;
    scan_partial<<<nblocks, SCAN_TPB, 0, stream>>>(cur, nrows, ptr, bsums);
    scan_blocksums<<<1, SCAN_TPB, 0, stream>>>(bsums, nblocks);
    scan_add<<<(nrows + 255) / 256, 256, 0, stream>>>(ptr, cur, nrows, nnz, bsums);
    csr_fill<<<(nnz + 255) / 256, 256, 0, stream>>>(rows, cols, vals, nnz, cur, ecv);
}

extern "C" void kernel_launch(void* const* d_in, const int* in_sizes, int n_in,
                              void* d_out, int out_size, void* d_ws, size_t ws_size,
                              hipStream_t stream) {
    const float* user_emb  = (const float*)d_in[0];
    const float* item_emb  = (const float*)d_in[1];
    const float* w_r1_w    = (const float*)d_in[2];
    const float* w_r1_b    = (const float*)d_in[3];
    const float* social_w1 = (const float*)d_in[4];
    const float* user_w1   = (const float*)d_in[5];
    const float* item_w1   = (const float*)d_in[6];
    const float* alpha     = (const float*)d_in[7];
    const float* social_vals = (const float*)d_in[8];
    const float* adj_vals    = (const float*)d_in[9];
    const int* social_rows = (const int*)d_in[10];
    const int* social_cols = (const int*)d_in[11];
    const int* adj_rows    = (const int*)d_in[12];
    const int* adj_cols    = (const int*)d_in[13];
    float* out = (float*)d_out;

    float* A  = (float*)d_ws;              // raw0 -> ego1
    float* B  = A + (size_t)NU5 * DD;      // t1 -> u
    float* C  = B + (size_t)NU5 * DD;      // raw1 -> emb1raw
    float* Dm = C + (size_t)NU5 * DD;      // embraw
    int*  s_ptr = (int*)(Dm + (size_t)NADJ * DD);
    int*  s_cur = s_ptr + (NU5 + 2);
    int2* s_ecv = (int2*)(s_cur + NU5);
    int*  a_ptr = (int*)(s_ecv + NNZ_S);
    int*  a_cur = a_ptr + (NADJ + 2);
    int2* a_ecv = (int2*)(a_cur + NADJ);
    int*  bsums = (int*)(a_ecv + NNZ_A);
    size_t need = (size_t)((char*)(bsums + 128) - (char*)d_ws);

    if (ws_size >= need) {
        build_csr(social_rows, social_cols, social_vals, NNZ_S, NU5,
                  s_ptr, s_cur, s_ecv, bsums, stream);
        build_csr(adj_rows, adj_cols, adj_vals, NNZ_A, NADJ,
                  a_ptr, a_cur, a_ecv, bsums, stream);

        spmm_csr<false><<<(NU5 * 64 + 255) / 256, 256, 0, stream>>>(
            s_ptr, s_ecv, user_emb, nullptr, A, NU5);
        gemm64_prelu<<<(NU5 + 63) / 64, 256, 0, stream>>>(A, social_w1, alpha, B, NU5);
        spmm_csr<false><<<(NU5 * 64 + 255) / 256, 256, 0, stream>>>(
            s_ptr, s_ecv, B, nullptr, C, NU5);
        fuse_u<<<(NUu + 63) / 64, 256, 0, stream>>>(A, C, w_r1_w, w_r1_b, alpha, B);
        spmm_csr<true><<<(NADJ * 64 + 255) / 256, 256, 0, stream>>>(
            a_ptr, a_ecv, B, item_emb, Dm, NADJ);
        fuse_ego1<<<(NADJ + 63) / 64, 256, 0, stream>>>(Dm, user_w1, item_w1, alpha, A);
        spmm_csr<false><<<(NADJ * 64 + 255) / 256, 256, 0, stream>>>(
            a_ptr, a_ecv, A, nullptr, C, NADJ);
    } else {
        hipMemsetAsync(A, 0, (size_t)NU5 * DD * sizeof(float), stream);
        spmm_atomic<<<(NNZ_S * 16 + 255) / 256, 256, 0, stream>>>(
            social_rows, social_cols, social_vals, user_emb, A, NNZ_S);
        gemm64_prelu<<<(NU5 + 63) / 64, 256, 0, stream>>>(A, social_w1, alpha, B, NU5);
        hipMemsetAsync(C, 0, (size_t)NU5 * DD * sizeof(float), stream);
        spmm_atomic<<<(NNZ_S * 16 + 255) / 256, 256, 0, stream>>>(
            social_rows, social_cols, social_vals, B, C, NNZ_S);
        fuse_u<<<(NUu + 63) / 64, 256, 0, stream>>>(A, C, w_r1_w, w_r1_b, alpha, B);
        hipMemcpyAsync(B + (size_t)NUu * DD, item_emb, (size_t)NI5 * DD * sizeof(float),
                       hipMemcpyDeviceToDevice, stream);
        hipMemsetAsync(Dm, 0, (size_t)NADJ * DD * sizeof(float), stream);
        spmm_atomic<<<(NNZ_A * 16 + 255) / 256, 256, 0, stream>>>(
            adj_rows, adj_cols, adj_vals, B, Dm, NNZ_A);
        fuse_ego1<<<(NADJ + 63) / 64, 256, 0, stream>>>(Dm, user_w1, item_w1, alpha, A);
        hipMemsetAsync(C, 0, (size_t)NADJ * DD * sizeof(float), stream);
        spmm_atomic<<<(NNZ_A * 16 + 255) / 256, 256, 0, stream>>>(
            adj_rows, adj_cols, adj_vals, A, C, NNZ_A);
    }

    out_combined<<<((NUu + NIi) * DD + 255) / 256, 256, 0, stream>>>(Dm, C, alpha, out);
}

// Round 7
// 700.242 us; speedup vs baseline: 1.5543x; 1.0556x over previous
//
#include <hip/hip_runtime.h>
#include <hip/hip_bf16.h>

#define NUu 30000
#define NIi 15000
#define DD 64
#define RR 5
#define NU5 150000
#define NI5 75000
#define NADJ 105000
#define NNZ_S 1200000
#define NNZ_A 840000

#define SCAN_TPB 256
#define SCAN_ELEMS 8
#define SCAN_CHUNK (SCAN_TPB * SCAN_ELEMS)  // 2048

#define NBK 256       // max buckets for partition
#define CHUNK 2048    // edges per partition block
#define CAP_S 10240   // bucket capacity social (exp 8192, +25%)
#define CAP_A 5120    // bucket capacity adj (exp 4096, +25%)
#define NBUCK_S ((NU5 + 1023) >> 10)   // 147
#define NBUCK_A ((NADJ + 511) >> 9)    // 206

// ============================ scan kernels ============================
__global__ void scan_partial(const int* __restrict__ counts, int n,
                             int* __restrict__ ptr, int* __restrict__ blocksums) {
    __shared__ int sh[SCAN_TPB];
    int base = blockIdx.x * SCAN_CHUNK;
    int t = threadIdx.x;
    int loc[SCAN_ELEMS];
    int s = 0;
#pragma unroll
    for (int i = 0; i < SCAN_ELEMS; ++i) {
        int idx = base + t * SCAN_ELEMS + i;
        int v = (idx < n) ? counts[idx] : 0;
        loc[i] = s;
        s += v;
    }
    sh[t] = s;
    __syncthreads();
    for (int off = 1; off < SCAN_TPB; off <<= 1) {
        int v = (t >= off) ? sh[t - off] : 0;
        __syncthreads();
        sh[t] += v;
        __syncthreads();
    }
    int texcl = (t == 0) ? 0 : sh[t - 1];
    if (t == SCAN_TPB - 1) blocksums[blockIdx.x] = sh[t];
#pragma unroll
    for (int i = 0; i < SCAN_ELEMS; ++i) {
        int idx = base + t * SCAN_ELEMS + i;
        if (idx < n) ptr[idx] = texcl + loc[i];
    }
}

__global__ void scan_blocksums(int* __restrict__ blocksums, int nblocks) {
    __shared__ int sh[SCAN_TPB];
    int t = threadIdx.x;
    int v = (t < nblocks) ? blocksums[t] : 0;
    sh[t] = v;
    __syncthreads();
    for (int off = 1; off < SCAN_TPB; off <<= 1) {
        int u = (t >= off) ? sh[t - off] : 0;
        __syncthreads();
        sh[t] += u;
        __syncthreads();
    }
    int excl = (t == 0) ? 0 : sh[t - 1];
    if (t < nblocks) blocksums[t] = excl;
}

__global__ void scan_add(int* __restrict__ ptr, int* __restrict__ cursor, int n, int nnz,
                         const int* __restrict__ blocksums) {
    int i = blockIdx.x * blockDim.x + threadIdx.x;
    if (i < n) {
        int v = ptr[i] + blocksums[i / SCAN_CHUNK];
        ptr[i] = v;
        cursor[i] = v;
    }
    if (i == 0) ptr[n] = nnz;
}

// ============== pass A: LDS multi-split partition + degree histogram ==============
template <int SH>
__global__ __launch_bounds__(256) void partition_edges(
    const int* __restrict__ rows, const int* __restrict__ cols,
    const float* __restrict__ vals, int nnz, int* __restrict__ counts,
    int* __restrict__ gcur, int4* __restrict__ part, int cap) {
    __shared__ int4 stage[CHUNK];                       // 32 KB
    __shared__ int hist[NBK], start[NBK], gbase[NBK], lcur[NBK];
    int t = threadIdx.x;
    int base = blockIdx.x * CHUNK;
    int nrem = nnz - base;
    int n = nrem < CHUNK ? nrem : CHUNK;
    hist[t] = 0;
    __syncthreads();
    int r[8], c[8];
    float v[8];
#pragma unroll
    for (int k = 0; k < 8; ++k) {
        int li = t + k * 256;
        if (li < n) {
            int i = base + li;
            r[k] = rows[i];
            c[k] = cols[i];
            v[k] = vals[i];
            atomicAdd(&hist[r[k] >> SH], 1);
            atomicAdd(&counts[r[k]], 1);  // global degree histogram (was csr_count)
        } else {
            r[k] = -1;
        }
    }
    __syncthreads();
    // exclusive scan hist -> start (Hillis-Steele, NBK == blockDim)
    int hv = hist[t];
    start[t] = hv;
    __syncthreads();
    for (int off = 1; off < NBK; off <<= 1) {
        int u = (t >= off) ? start[t - off] : 0;
        __syncthreads();
        start[t] += u;
        __syncthreads();
    }
    int excl = start[t] - hv;
    __syncthreads();
    start[t] = excl;
    lcur[t] = excl;
    gbase[t] = (hv > 0) ? atomicAdd(&gcur[t], hv) : 0;
    __syncthreads();
    // scatter into LDS staging
#pragma unroll
    for (int k = 0; k < 8; ++k) {
        if (r[k] >= 0) {
            int b = r[k] >> SH;
            int p = atomicAdd(&lcur[b], 1);
            stage[p] = make_int4(r[k], c[k], __float_as_int(v[k]), 0);
        }
    }
    __syncthreads();
    // flush: bucket-contiguous coalesced global writes
    for (int j = t; j < n; j += 256) {
        int4 e = stage[j];
        int b = e.x >> SH;
        part[(size_t)b * cap + gbase[b] + (j - start[b])] = e;
    }
}

// ============== pass B: per-bucket fill; scattered writes stay L2-resident ==============
__global__ __launch_bounds__(256) void bucket_fill(
    const int4* __restrict__ part, const int* __restrict__ gcur, int cap,
    int* __restrict__ cursor, int2* __restrict__ ecv) {
    int b = blockIdx.x;
    int cnt = gcur[b];
    const int4* seg = part + (size_t)b * cap;
    for (int j = threadIdx.x; j < cnt; j += 256) {
        int4 e = seg[j];
        int p = atomicAdd(&cursor[e.x], 1);
        ecv[p] = make_int2(e.y, e.z);
    }
}

// ============== SpMM (CSR gather): one wave per row, lane = component ==============
template <bool SPLIT>
__global__ void spmm_csr(const int* __restrict__ ptr, const int2* __restrict__ ecv,
                         const float* __restrict__ x, const float* __restrict__ x2,
                         float* __restrict__ out, int nrows) {
    int w = (blockIdx.x * blockDim.x + threadIdx.x) >> 6;
    int lane = threadIdx.x & 63;
    if (w >= nrows) return;
    int beg = ptr[w], end = ptr[w + 1];
    float a0 = 0.f, a1 = 0.f, a2 = 0.f, a3 = 0.f;
    int j = beg;
    for (; j + 3 < end; j += 4) {
        int2 e0 = ecv[j], e1 = ecv[j + 1], e2 = ecv[j + 2], e3 = ecv[j + 3];
        const float *p0, *p1, *p2, *p3;
        if (SPLIT) {
            p0 = (e0.x < NUu) ? x + (size_t)e0.x * DD : x2 + (size_t)(e0.x - NUu) * DD;
            p1 = (e1.x < NUu) ? x + (size_t)e1.x * DD : x2 + (size_t)(e1.x - NUu) * DD;
            p2 = (e2.x < NUu) ? x + (size_t)e2.x * DD : x2 + (size_t)(e2.x - NUu) * DD;
            p3 = (e3.x < NUu) ? x + (size_t)e3.x * DD : x2 + (size_t)(e3.x - NUu) * DD;
        } else {
            p0 = x + (size_t)e0.x * DD;
            p1 = x + (size_t)e1.x * DD;
            p2 = x + (size_t)e2.x * DD;
            p3 = x + (size_t)e3.x * DD;
        }
        a0 += __int_as_float(e0.y) * p0[lane];
        a1 += __int_as_float(e1.y) * p1[lane];
        a2 += __int_as_float(e2.y) * p2[lane];
        a3 += __int_as_float(e3.y) * p3[lane];
    }
    for (; j < end; ++j) {
        int2 e0 = ecv[j];
        const float* p0;
        if (SPLIT)
            p0 = (e0.x < NUu) ? x + (size_t)e0.x * DD : x2 + (size_t)(e0.x - NUu) * DD;
        else
            p0 = x + (size_t)e0.x * DD;
        a0 += __int_as_float(e0.y) * p0[lane];
    }
    out[(size_t)w * DD + lane] = (a0 + a1) + (a2 + a3);
}

// ============== fallback: atomic SpMM (if ws too small for CSR) ==============
__global__ void spmm_atomic(const int* __restrict__ rows, const int* __restrict__ cols,
                            const float* __restrict__ vals, const float* __restrict__ x,
                            float* __restrict__ out, int nnz) {
    int tid = blockIdx.x * blockDim.x + threadIdx.x;
    int e = tid >> 4;
    if (e >= nnz) return;
    int lc = (tid & 15) << 2;
    int r = rows[e];
    int c = cols[e];
    float v = vals[e];
    const float4 xv = *reinterpret_cast<const float4*>(x + (size_t)c * DD + lc);
    float* o = out + (size_t)r * DD + lc;
    unsafeAtomicAdd(o + 0, v * xv.x);
    unsafeAtomicAdd(o + 1, v * xv.y);
    unsafeAtomicAdd(o + 2, v * xv.z);
    unsafeAtomicAdd(o + 3, v * xv.w);
}

// ============== dense kernels: row-per-thread, W broadcast from LDS ==============
#define PRELU(v) ((v) >= 0.f ? (v) : alpha * (v))

__global__ void gemm64_prelu(const float* __restrict__ X, const float* __restrict__ W,
                             const float* __restrict__ alpha_p, float* __restrict__ Y,
                             int nrows) {
    __shared__ float4 Ws[64 * 16];
    int t = threadIdx.x;
    {
        const float4* Wv = (const float4*)W;
        for (int i = t; i < 1024; i += 256) Ws[i] = Wv[i];
    }
    __syncthreads();
    float alpha = alpha_p[0];
    int lane = t & 63;
    int g = t >> 6;
    int row = blockIdx.x * 64 + lane;
    if (row >= nrows) return;

    float xr[64];
    const float4* xp = (const float4*)(X + (size_t)row * DD);
#pragma unroll
    for (int i = 0; i < 16; ++i) {
        float4 v = xp[i];
        xr[4 * i + 0] = PRELU(v.x);
        xr[4 * i + 1] = PRELU(v.y);
        xr[4 * i + 2] = PRELU(v.z);
        xr[4 * i + 3] = PRELU(v.w);
    }
    float4 a0 = {0, 0, 0, 0}, a1 = a0, a2 = a0, a3 = a0;
#pragma unroll
    for (int k = 0; k < 64; ++k) {
        float xk = xr[k];
        const float4* wr = &Ws[k * 16 + g * 4];
        float4 w0 = wr[0], w1 = wr[1], w2 = wr[2], w3 = wr[3];
        a0.x += xk * w0.x; a0.y += xk * w0.y; a0.z += xk * w0.z; a0.w += xk * w0.w;
        a1.x += xk * w1.x; a1.y += xk * w1.y; a1.z += xk * w1.z; a1.w += xk * w1.w;
        a2.x += xk * w2.x; a2.y += xk * w2.y; a2.z += xk * w2.z; a2.w += xk * w2.w;
        a3.x += xk * w3.x; a3.y += xk * w3.y; a3.z += xk * w3.z; a3.w += xk * w3.w;
    }
    float4* yp = (float4*)(Y + (size_t)row * DD + g * 16);
    yp[0] = a0; yp[1] = a1; yp[2] = a2; yp[3] = a3;
}

__global__ void fuse_u(const float* __restrict__ raw0, const float* __restrict__ raw1,
                       const float* __restrict__ w_r1_w, const float* __restrict__ w_r1_b,
                       const float* __restrict__ alpha_p, float* __restrict__ uout) {
    __shared__ float Wl[128 * 68];
    int t = threadIdx.x;
    for (int i = t; i < 8192; i += 256) {
        int j = i >> 7, k = i & 127;
        Wl[k * 68 + j] = w_r1_w[i];
    }
    __syncthreads();
    float alpha = alpha_p[0];
    int lane = t & 63;
    int g = t >> 6;
    int row = blockIdx.x * 64 + lane;
    if (row >= NUu) return;

    const float4* bp = (const float4*)(w_r1_b + g * 16);
    float4 a0 = bp[0], a1 = bp[1], a2 = bp[2], a3 = bp[3];
    float xr[64];

    const float4* rp = (const float4*)(raw0 + (size_t)row * RR * DD);
#pragma unroll
    for (int i = 0; i < 16; ++i) {
        float sx = 0.f, sy = 0.f, sz = 0.f, sw = 0.f;
#pragma unroll
        for (int r = 0; r < RR; ++r) {
            float4 v = rp[r * 16 + i];
            sx += PRELU(v.x); sy += PRELU(v.y); sz += PRELU(v.z); sw += PRELU(v.w);
        }
        xr[4 * i + 0] = sx * 0.25f;
        xr[4 * i + 1] = sy * 0.25f;
        xr[4 * i + 2] = sz * 0.25f;
        xr[4 * i + 3] = sw * 0.25f;
    }
#pragma unroll
    for (int k = 0; k < 64; ++k) {
        float xk = xr[k];
        const float4* wr = (const float4*)(Wl + k * 68 + g * 16);
        float4 w0 = wr[0], w1 = wr[1], w2 = wr[2], w3 = wr[3];
        a0.x += xk * w0.x; a0.y += xk * w0.y; a0.z += xk * w0.z; a0.w += xk * w0.w;
        a1.x += xk * w1.x; a1.y += xk * w1.y; a1.z += xk * w1.z; a1.w += xk * w1.w;
        a2.x += xk * w2.x; a2.y += xk * w2.y; a2.z += xk * w2.z; a2.w += xk * w2.w;
        a3.x += xk * w3.x; a3.y += xk * w3.y; a3.z += xk * w3.z; a3.w += xk * w3.w;
    }
    rp = (const float4*)(raw1 + (size_t)row * RR * DD);
#pragma unroll
    for (int i = 0; i < 16; ++i) {
        float sx = 0.f, sy = 0.f, sz = 0.f, sw = 0.f;
#pragma unroll
        for (int r = 0; r < RR; ++r) {
            float4 v = rp[r * 16 + i];
            sx += PRELU(v.x); sy += PRELU(v.y); sz += PRELU(v.z); sw += PRELU(v.w);
        }
        xr[4 * i + 0] = sx * 0.25f;
        xr[4 * i + 1] = sy * 0.25f;
        xr[4 * i + 2] = sz * 0.25f;
        xr[4 * i + 3] = sw * 0.25f;
    }
#pragma unroll
    for (int k = 0; k < 64; ++k) {
        float xk = xr[k];
        const float4* wr = (const float4*)(Wl + (64 + k) * 68 + g * 16);
        float4 w0 = wr[0], w1 = wr[1], w2 = wr[2], w3 = wr[3];
        a0.x += xk * w0.x; a0.y += xk * w0.y; a0.z += xk * w0.z; a0.w += xk * w0.w;
        a1.x += xk * w1.x; a1.y += xk * w1.y; a1.z += xk * w1.z; a1.w += xk * w1.w;
        a2.x += xk * w2.x; a2.y += xk * w2.y; a2.z += xk * w2.z; a2.w += xk * w2.w;
        a3.x += xk * w3.x; a3.y += xk * w3.y; a3.z += xk * w3.z; a3.w += xk * w3.w;
    }
    float4* yp = (float4*)(uout + (size_t)row * DD + g * 16);
    yp[0] = a0; yp[1] = a1; yp[2] = a2; yp[3] = a3;
}

__global__ void fuse_ego1(const float* __restrict__ embraw, const float* __restrict__ Wu,
                          const float* __restrict__ Wi, const float* __restrict__ alpha_p,
                          float* __restrict__ ego1) {
    __shared__ float4 Ws[2 * 64 * 16];
    int t = threadIdx.x;
    {
        const float4* Wv = (const float4*)Wu;
        const float4* Wv2 = (const float4*)Wi;
        for (int i = t; i < 1024; i += 256) {
            Ws[i] = Wv[i];
            Ws[1024 + i] = Wv2[i];
        }
    }
    __syncthreads();
    float alpha = alpha_p[0];
    int lane = t & 63;
    int g = t >> 6;
    int row = blockIdx.x * 64 + lane;
    if (row >= NADJ) return;
    const float4* Wb = (row < NUu) ? Ws : Ws + 1024;

    float xr[64];
    const float4* xp = (const float4*)(embraw + (size_t)row * DD);
#pragma unroll
    for (int i = 0; i < 16; ++i) {
        float4 v = xp[i];
        xr[4 * i + 0] = PRELU(v.x);
        xr[4 * i + 1] = PRELU(v.y);
        xr[4 * i + 2] = PRELU(v.z);
        xr[4 * i + 3] = PRELU(v.w);
    }
    float4 a0 = {0, 0, 0, 0}, a1 = a0, a2 = a0, a3 = a0;
#pragma unroll
    for (int k = 0; k < 64; ++k) {
        float xk = xr[k];
        const float4* wr = &Wb[k * 16 + g * 4];
        float4 w0 = wr[0], w1 = wr[1], w2 = wr[2], w3 = wr[3];
        a0.x += xk * w0.x; a0.y += xk * w0.y; a0.z += xk * w0.z; a0.w += xk * w0.w;
        a1.x += xk * w1.x; a1.y += xk * w1.y; a1.z += xk * w1.z; a1.w += xk * w1.w;
        a2.x += xk * w2.x; a2.y += xk * w2.y; a2.z += xk * w2.z; a2.w += xk * w2.w;
        a3.x += xk * w3.x; a3.y += xk * w3.y; a3.z += xk * w3.z; a3.w += xk * w3.w;
    }
    float4* yp = (float4*)(ego1 + (size_t)row * DD + g * 16);
    yp[0] = a0; yp[1] = a1; yp[2] = a2; yp[3] = a3;
}

// ============== outputs (users + items in one kernel) ==============
__global__ void out_combined(const float* __restrict__ embraw, const float* __restrict__ emb1raw,
                             const float* __restrict__ alpha_p, float* __restrict__ outp) {
    float alpha = alpha_p[0];
    int i = blockIdx.x * blockDim.x + threadIdx.x;
    if (i < NUu * DD) {
        int row = i >> 6, c = i & 63;
        float a = embraw[i];
        a = PRELU(a);
        float b = emb1raw[i];
        b = PRELU(b);
        outp[(size_t)row * 128 + c] = a;
        outp[(size_t)row * 128 + 64 + c] = b;
    } else {
        int i2 = i - NUu * DD;
        if (i2 >= NIi * DD) return;
        int row = i2 >> 6, c = i2 & 63;
        float s0 = 0.f, s1 = 0.f;
#pragma unroll
        for (int r = 0; r < RR; ++r) {
            size_t idx = ((size_t)NUu + (size_t)row * RR + r) * DD + c;
            float a = embraw[idx];
            s0 += PRELU(a);
            float b = emb1raw[idx];
            s1 += PRELU(b);
        }
        size_t obase = (size_t)NUu * 128 + (size_t)row * 128 + c;
        outp[obase] = s0 / 5.0f;
        outp[obase + 64] = s1 / 5.0f;
    }
}

// ============================ host ============================
extern "C" void kernel_launch(void* const* d_in, const int* in_sizes, int n_in,
                              void* d_out, int out_size, void* d_ws, size_t ws_size,
                              hipStream_t stream) {
    const float* user_emb  = (const float*)d_in[0];
    const float* item_emb  = (const float*)d_in[1];
    const float* w_r1_w    = (const float*)d_in[2];
    const float* w_r1_b    = (const float*)d_in[3];
    const float* social_w1 = (const float*)d_in[4];
    const float* user_w1   = (const float*)d_in[5];
    const float* item_w1   = (const float*)d_in[6];
    const float* alpha     = (const float*)d_in[7];
    const float* social_vals = (const float*)d_in[8];
    const float* adj_vals    = (const float*)d_in[9];
    const int* social_rows = (const int*)d_in[10];
    const int* social_cols = (const int*)d_in[11];
    const int* adj_rows    = (const int*)d_in[12];
    const int* adj_cols    = (const int*)d_in[13];
    float* out = (float*)d_out;

    float* A  = (float*)d_ws;              // part (during CSR build) -> raw0 -> ego1
    float* B  = A + (size_t)NU5 * DD;      // t1 -> u
    float* C  = B + (size_t)NU5 * DD;      // raw1 -> emb1raw
    float* Dm = C + (size_t)NU5 * DD;      // embraw
    int*  s_ptr = (int*)(Dm + (size_t)NADJ * DD);
    int*  s_cur = s_ptr + (NU5 + 2);
    int2* s_ecv = (int2*)(s_cur + NU5);
    int*  a_ptr = (int*)(s_ecv + NNZ_S);
    int*  a_cur = a_ptr + (NADJ + 2);
    int2* a_ecv = (int2*)(a_cur + NADJ);
    int*  bsums = (int*)(a_ecv + NNZ_A);
    int*  gcur  = bsums + 128;
    size_t need = (size_t)((char*)(gcur + NBK) - (char*)d_ws);
    int4* part = (int4*)A;  // aliases A: dead until first spmm writes raw0

    if (ws_size >= need) {
        // ---- social CSR build ----
        hipMemsetAsync(s_cur, 0, (size_t)NU5 * sizeof(int), stream);
        hipMemsetAsync(gcur, 0, NBK * sizeof(int), stream);
        partition_edges<10><<<(NNZ_S + CHUNK - 1) / CHUNK, 256, 0, stream>>>(
            social_rows, social_cols, social_vals, NNZ_S, s_cur, gcur, part, CAP_S);
        {
            int nblocks = (NU5 + SCAN_CHUNK - 1) / SCAN_CHUNK;
            scan_partial<<<nblocks, SCAN_TPB, 0, stream>>>(s_cur, NU5, s_ptr, bsums);
            scan_blocksums<<<1, SCAN_TPB, 0, stream>>>(bsums, nblocks);
            scan_add<<<(NU5 + 255) / 256, 256, 0, stream>>>(s_ptr, s_cur, NU5, NNZ_S, bsums);
        }
        bucket_fill<<<NBUCK_S, 256, 0, stream>>>(part, gcur, CAP_S, s_cur, s_ecv);

        // ---- adj CSR build ----
        hipMemsetAsync(a_cur, 0, (size_t)NADJ * sizeof(int), stream);
        hipMemsetAsync(gcur, 0, NBK * sizeof(int), stream);
        partition_edges<9><<<(NNZ_A + CHUNK - 1) / CHUNK, 256, 0, stream>>>(
            adj_rows, adj_cols, adj_vals, NNZ_A, a_cur, gcur, part, CAP_A);
        {
            int nblocks = (NADJ + SCAN_CHUNK - 1) / SCAN_CHUNK;
            scan_partial<<<nblocks, SCAN_TPB, 0, stream>>>(a_cur, NADJ, a_ptr, bsums);
            scan_blocksums<<<1, SCAN_TPB, 0, stream>>>(bsums, nblocks);
            scan_add<<<(NADJ + 255) / 256, 256, 0, stream>>>(a_ptr, a_cur, NADJ, NNZ_A, bsums);
        }
        bucket_fill<<<NBUCK_A, 256, 0, stream>>>(part, gcur, CAP_A, a_cur, a_ecv);

        // ---- pipeline ----
        spmm_csr<false><<<(NU5 * 64 + 255) / 256, 256, 0, stream>>>(
            s_ptr, s_ecv, user_emb, nullptr, A, NU5);
        gemm64_prelu<<<(NU5 + 63) / 64, 256, 0, stream>>>(A, social_w1, alpha, B, NU5);
        spmm_csr<false><<<(NU5 * 64 + 255) / 256, 256, 0, stream>>>(
            s_ptr, s_ecv, B, nullptr, C, NU5);
        fuse_u<<<(NUu + 63) / 64, 256, 0, stream>>>(A, C, w_r1_w, w_r1_b, alpha, B);
        spmm_csr<true><<<(NADJ * 64 + 255) / 256, 256, 0, stream>>>(
            a_ptr, a_ecv, B, item_emb, Dm, NADJ);
        fuse_ego1<<<(NADJ + 63) / 64, 256, 0, stream>>>(Dm, user_w1, item_w1, alpha, A);
        spmm_csr<false><<<(NADJ * 64 + 255) / 256, 256, 0, stream>>>(
            a_ptr, a_ecv, A, nullptr, C, NADJ);
    } else {
        // ---- atomic fallback ----
        hipMemsetAsync(A, 0, (size_t)NU5 * DD * sizeof(float), stream);
        spmm_atomic<<<(NNZ_S * 16 + 255) / 256, 256, 0, stream>>>(
            social_rows, social_cols, social_vals, user_emb, A, NNZ_S);
        gemm64_prelu<<<(NU5 + 63) / 64, 256, 0, stream>>>(A, social_w1, alpha, B, NU5);
        hipMemsetAsync(C, 0, (size_t)NU5 * DD * sizeof(float), stream);
        spmm_atomic<<<(NNZ_S * 16 + 255) / 256, 256, 0, stream>>>(
            social_rows, social_cols, social_vals, B, C, NNZ_S);
        fuse_u<<<(NUu + 63) / 64, 256, 0, stream>>>(A, C, w_r1_w, w_r1_b, alpha, B);
        hipMemcpyAsync(B + (size_t)NUu * DD, item_emb, (size_t)NI5 * DD * sizeof(float),
                       hipMemcpyDeviceToDevice, stream);
        hipMemsetAsync(Dm, 0, (size_t)NADJ * DD * sizeof(float), stream);
        spmm_atomic<<<(NNZ_A * 16 + 255) / 256, 256, 0, stream>>>(
            adj_rows, adj_cols, adj_vals, B, Dm, NNZ_A);
        fuse_ego1<<<(NADJ + 63) / 64, 256, 0, stream>>>(Dm, user_w1, item_w1, alpha, A);
        hipMemsetAsync(C, 0, (size_t)NADJ * DD * sizeof(float), stream);
        spmm_atomic<<<(NNZ_A * 16 + 255) / 256, 256, 0, stream>>>(
            adj_rows, adj_cols, adj_vals, A, C, NNZ_A);
    }

    out_combined<<<((NUu + NIi) * DD + 255) / 256, 256, 0, stream>>>(Dm, C, alpha, out);
}

// Round 8
// 595.520 us; speedup vs baseline: 1.8276x; 1.1758x over previous
//
#include <hip/hip_runtime.h>
#include <hip/hip_bf16.h>

#define NUu 30000
#define NIi 15000
#define DD 64
#define RR 5
#define NU5 150000
#define NI5 75000
#define NADJ 105000
#define NNZ_S 1200000
#define NNZ_A 840000

#define NBK 256       // max buckets for partition
#define CHUNK 2048    // edges per partition block
#define CAP_S 10240   // bucket capacity social (exp 8163, +25%)
#define CAP_A 5120    // bucket capacity adj (exp 4078, +25%)
#define NBUCK_S ((NU5 + 1023) >> 10)   // 147
#define NBUCK_A ((NADJ + 511) >> 9)    // 206

// ============== pass A: LDS multi-split partition ==============
template <int SH>
__global__ __launch_bounds__(256) void partition_edges(
    const int* __restrict__ rows, const int* __restrict__ cols,
    const float* __restrict__ vals, int nnz,
    int* __restrict__ gcur, int4* __restrict__ part, int cap) {
    __shared__ int4 stage[CHUNK];                       // 32 KB
    __shared__ int hist[NBK], start[NBK], gbase[NBK], lcur[NBK];
    int t = threadIdx.x;
    int base = blockIdx.x * CHUNK;
    int nrem = nnz - base;
    int n = nrem < CHUNK ? nrem : CHUNK;
    hist[t] = 0;
    __syncthreads();
    int r[8], c[8];
    float v[8];
#pragma unroll
    for (int k = 0; k < 8; ++k) {
        int li = t + k * 256;
        if (li < n) {
            int i = base + li;
            r[k] = rows[i];
            c[k] = cols[i];
            v[k] = vals[i];
            atomicAdd(&hist[r[k] >> SH], 1);
        } else {
            r[k] = -1;
        }
    }
    __syncthreads();
    // exclusive scan hist -> start (Hillis-Steele over 256)
    int hv = hist[t];
    start[t] = hv;
    __syncthreads();
    for (int off = 1; off < NBK; off <<= 1) {
        int u = (t >= off) ? start[t - off] : 0;
        __syncthreads();
        start[t] += u;
        __syncthreads();
    }
    int excl = start[t] - hv;
    __syncthreads();
    start[t] = excl;
    lcur[t] = excl;
    gbase[t] = (hv > 0) ? atomicAdd(&gcur[t], hv) : 0;
    __syncthreads();
    // scatter into LDS staging
#pragma unroll
    for (int k = 0; k < 8; ++k) {
        if (r[k] >= 0) {
            int b = r[k] >> SH;
            int p = atomicAdd(&lcur[b], 1);
            stage[p] = make_int4(r[k], c[k], __float_as_int(v[k]), 0);
        }
    }
    __syncthreads();
    // flush: bucket-contiguous coalesced global writes
    for (int j = t; j < n; j += 256) {
        int4 e = stage[j];
        int b = e.x >> SH;
        part[(size_t)b * cap + gbase[b] + (j - start[b])] = e;
    }
}

// ============== bucket-total scan (both matrices, one launch) ==============
__global__ void scan_buckets(const int* __restrict__ gcur_s, int* __restrict__ gbase_s,
                             int* __restrict__ sptr,
                             const int* __restrict__ gcur_a, int* __restrict__ gbase_a,
                             int* __restrict__ aptr) {
    __shared__ int sh[256];
    int t = threadIdx.x;
    const int* gc = (blockIdx.x == 0) ? gcur_s : gcur_a;
    int* gb = (blockIdx.x == 0) ? gbase_s : gbase_a;
    int nb = (blockIdx.x == 0) ? NBUCK_S : NBUCK_A;
    int v = (t < nb) ? gc[t] : 0;
    sh[t] = v;
    __syncthreads();
    for (int off = 1; off < 256; off <<= 1) {
        int u = (t >= off) ? sh[t - off] : 0;
        __syncthreads();
        sh[t] += u;
        __syncthreads();
    }
    if (t < nb) gb[t] = sh[t] - v;  // exclusive
    if (t == 0) {
        if (blockIdx.x == 0) sptr[NU5] = NNZ_S;
        else aptr[NADJ] = NNZ_A;
    }
}

// ============== pass B: per-bucket LDS counting sort -> ptr + ecv ==============
template <int SH>
__global__ __launch_bounds__(256) void bucket_sort_fill(
    const int4* __restrict__ part, const int* __restrict__ gcur,
    const int* __restrict__ gbase, int cap, int nrows,
    int* __restrict__ ptr, int2* __restrict__ ecv) {
    constexpr int NR = 1 << SH;      // rows per bucket (1024 or 512)
    constexpr int E = NR / 256;      // rows per thread
    __shared__ int hist[NR];
    __shared__ int tsum[256];
    int b = blockIdx.x;
    int t = threadIdx.x;
    int base_r = b << SH;
    int cnt = gcur[b];
    int gb = gbase[b];
    const int4* seg = part + (size_t)b * cap;
#pragma unroll
    for (int i = 0; i < E; ++i) hist[t * E + i] = 0;
    __syncthreads();
    // pass 1: count rows (LDS atomics, bucket-local)
    for (int j = t; j < cnt; j += 256) atomicAdd(&hist[seg[j].x - base_r], 1);
    __syncthreads();
    // exclusive scan over NR: per-thread sequential + Hillis-Steele over thread sums
    int loc[E];
    int s = 0;
#pragma unroll
    for (int i = 0; i < E; ++i) {
        loc[i] = s;
        s += hist[t * E + i];
    }
    tsum[t] = s;
    __syncthreads();
    for (int off = 1; off < 256; off <<= 1) {
        int u = (t >= off) ? tsum[t - off] : 0;
        __syncthreads();
        tsum[t] += u;
        __syncthreads();
    }
    int texcl = (t == 0) ? 0 : tsum[t - 1];
    // write ptr; convert hist to cursors (each thread owns its E slots)
#pragma unroll
    for (int i = 0; i < E; ++i) {
        int excl = texcl + loc[i];
        int row = base_r + t * E + i;
        if (row < nrows) ptr[row] = gb + excl;
        hist[t * E + i] = excl;
    }
    __syncthreads();
    // pass 2: scatter (LDS cursor atomics; ecv writes land in L2-resident window)
    for (int j = t; j < cnt; j += 256) {
        int4 e = seg[j];
        int p = gb + atomicAdd(&hist[e.x - base_r], 1);
        ecv[p] = make_int2(e.y, e.z);
    }
}

// ============== SpMM (CSR gather): one wave per row, lane = component ==============
template <bool SPLIT>
__global__ void spmm_csr(const int* __restrict__ ptr, const int2* __restrict__ ecv,
                         const float* __restrict__ x, const float* __restrict__ x2,
                         float* __restrict__ out, int nrows) {
    int w = (blockIdx.x * blockDim.x + threadIdx.x) >> 6;
    int lane = threadIdx.x & 63;
    if (w >= nrows) return;
    int beg = ptr[w], end = ptr[w + 1];
    float a0 = 0.f, a1 = 0.f, a2 = 0.f, a3 = 0.f;
    int j = beg;
    for (; j + 3 < end; j += 4) {
        int2 e0 = ecv[j], e1 = ecv[j + 1], e2 = ecv[j + 2], e3 = ecv[j + 3];
        const float *p0, *p1, *p2, *p3;
        if (SPLIT) {
            p0 = (e0.x < NUu) ? x + (size_t)e0.x * DD : x2 + (size_t)(e0.x - NUu) * DD;
            p1 = (e1.x < NUu) ? x + (size_t)e1.x * DD : x2 + (size_t)(e1.x - NUu) * DD;
            p2 = (e2.x < NUu) ? x + (size_t)e2.x * DD : x2 + (size_t)(e2.x - NUu) * DD;
            p3 = (e3.x < NUu) ? x + (size_t)e3.x * DD : x2 + (size_t)(e3.x - NUu) * DD;
        } else {
            p0 = x + (size_t)e0.x * DD;
            p1 = x + (size_t)e1.x * DD;
            p2 = x + (size_t)e2.x * DD;
            p3 = x + (size_t)e3.x * DD;
        }
        a0 += __int_as_float(e0.y) * p0[lane];
        a1 += __int_as_float(e1.y) * p1[lane];
        a2 += __int_as_float(e2.y) * p2[lane];
        a3 += __int_as_float(e3.y) * p3[lane];
    }
    for (; j < end; ++j) {
        int2 e0 = ecv[j];
        const float* p0;
        if (SPLIT)
            p0 = (e0.x < NUu) ? x + (size_t)e0.x * DD : x2 + (size_t)(e0.x - NUu) * DD;
        else
            p0 = x + (size_t)e0.x * DD;
        a0 += __int_as_float(e0.y) * p0[lane];
    }
    out[(size_t)w * DD + lane] = (a0 + a1) + (a2 + a3);
}

// ============== fallback: atomic SpMM (if ws too small) ==============
__global__ void spmm_atomic(const int* __restrict__ rows, const int* __restrict__ cols,
                            const float* __restrict__ vals, const float* __restrict__ x,
                            float* __restrict__ out, int nnz) {
    int tid = blockIdx.x * blockDim.x + threadIdx.x;
    int e = tid >> 4;
    if (e >= nnz) return;
    int lc = (tid & 15) << 2;
    int r = rows[e];
    int c = cols[e];
    float v = vals[e];
    const float4 xv = *reinterpret_cast<const float4*>(x + (size_t)c * DD + lc);
    float* o = out + (size_t)r * DD + lc;
    unsafeAtomicAdd(o + 0, v * xv.x);
    unsafeAtomicAdd(o + 1, v * xv.y);
    unsafeAtomicAdd(o + 2, v * xv.z);
    unsafeAtomicAdd(o + 3, v * xv.w);
}

// ============== dense kernels: row-per-thread, W broadcast from LDS ==============
#define PRELU(v) ((v) >= 0.f ? (v) : alpha * (v))

__global__ void gemm64_prelu(const float* __restrict__ X, const float* __restrict__ W,
                             const float* __restrict__ alpha_p, float* __restrict__ Y,
                             int nrows) {
    __shared__ float4 Ws[64 * 16];
    int t = threadIdx.x;
    {
        const float4* Wv = (const float4*)W;
        for (int i = t; i < 1024; i += 256) Ws[i] = Wv[i];
    }
    __syncthreads();
    float alpha = alpha_p[0];
    int lane = t & 63;
    int g = t >> 6;
    int row = blockIdx.x * 64 + lane;
    if (row >= nrows) return;

    float xr[64];
    const float4* xp = (const float4*)(X + (size_t)row * DD);
#pragma unroll
    for (int i = 0; i < 16; ++i) {
        float4 v = xp[i];
        xr[4 * i + 0] = PRELU(v.x);
        xr[4 * i + 1] = PRELU(v.y);
        xr[4 * i + 2] = PRELU(v.z);
        xr[4 * i + 3] = PRELU(v.w);
    }
    float4 a0 = {0, 0, 0, 0}, a1 = a0, a2 = a0, a3 = a0;
#pragma unroll
    for (int k = 0; k < 64; ++k) {
        float xk = xr[k];
        const float4* wr = &Ws[k * 16 + g * 4];
        float4 w0 = wr[0], w1 = wr[1], w2 = wr[2], w3 = wr[3];
        a0.x += xk * w0.x; a0.y += xk * w0.y; a0.z += xk * w0.z; a0.w += xk * w0.w;
        a1.x += xk * w1.x; a1.y += xk * w1.y; a1.z += xk * w1.z; a1.w += xk * w1.w;
        a2.x += xk * w2.x; a2.y += xk * w2.y; a2.z += xk * w2.z; a2.w += xk * w2.w;
        a3.x += xk * w3.x; a3.y += xk * w3.y; a3.z += xk * w3.z; a3.w += xk * w3.w;
    }
    float4* yp = (float4*)(Y + (size_t)row * DD + g * 16);
    yp[0] = a0; yp[1] = a1; yp[2] = a2; yp[3] = a3;
}

__global__ void fuse_u(const float* __restrict__ raw0, const float* __restrict__ raw1,
                       const float* __restrict__ w_r1_w, const float* __restrict__ w_r1_b,
                       const float* __restrict__ alpha_p, float* __restrict__ uout) {
    __shared__ float Wl[128 * 68];
    int t = threadIdx.x;
    for (int i = t; i < 8192; i += 256) {
        int j = i >> 7, k = i & 127;
        Wl[k * 68 + j] = w_r1_w[i];
    }
    __syncthreads();
    float alpha = alpha_p[0];
    int lane = t & 63;
    int g = t >> 6;
    int row = blockIdx.x * 64 + lane;
    if (row >= NUu) return;

    const float4* bp = (const float4*)(w_r1_b + g * 16);
    float4 a0 = bp[0], a1 = bp[1], a2 = bp[2], a3 = bp[3];
    float xr[64];

    const float4* rp = (const float4*)(raw0 + (size_t)row * RR * DD);
#pragma unroll
    for (int i = 0; i < 16; ++i) {
        float sx = 0.f, sy = 0.f, sz = 0.f, sw = 0.f;
#pragma unroll
        for (int r = 0; r < RR; ++r) {
            float4 v = rp[r * 16 + i];
            sx += PRELU(v.x); sy += PRELU(v.y); sz += PRELU(v.z); sw += PRELU(v.w);
        }
        xr[4 * i + 0] = sx * 0.25f;
        xr[4 * i + 1] = sy * 0.25f;
        xr[4 * i + 2] = sz * 0.25f;
        xr[4 * i + 3] = sw * 0.25f;
    }
#pragma unroll
    for (int k = 0; k < 64; ++k) {
        float xk = xr[k];
        const float4* wr = (const float4*)(Wl + k * 68 + g * 16);
        float4 w0 = wr[0], w1 = wr[1], w2 = wr[2], w3 = wr[3];
        a0.x += xk * w0.x; a0.y += xk * w0.y; a0.z += xk * w0.z; a0.w += xk * w0.w;
        a1.x += xk * w1.x; a1.y += xk * w1.y; a1.z += xk * w1.z; a1.w += xk * w1.w;
        a2.x += xk * w2.x; a2.y += xk * w2.y; a2.z += xk * w2.z; a2.w += xk * w2.w;
        a3.x += xk * w3.x; a3.y += xk * w3.y; a3.z += xk * w3.z; a3.w += xk * w3.w;
    }
    rp = (const float4*)(raw1 + (size_t)row * RR * DD);
#pragma unroll
    for (int i = 0; i < 16; ++i) {
        float sx = 0.f, sy = 0.f, sz = 0.f, sw = 0.f;
#pragma unroll
        for (int r = 0; r < RR; ++r) {
            float4 v = rp[r * 16 + i];
            sx += PRELU(v.x); sy += PRELU(v.y); sz += PRELU(v.z); sw += PRELU(v.w);
        }
        xr[4 * i + 0] = sx * 0.25f;
        xr[4 * i + 1] = sy * 0.25f;
        xr[4 * i + 2] = sz * 0.25f;
        xr[4 * i + 3] = sw * 0.25f;
    }
#pragma unroll
    for (int k = 0; k < 64; ++k) {
        float xk = xr[k];
        const float4* wr = (const float4*)(Wl + (64 + k) * 68 + g * 16);
        float4 w0 = wr[0], w1 = wr[1], w2 = wr[2], w3 = wr[3];
        a0.x += xk * w0.x; a0.y += xk * w0.y; a0.z += xk * w0.z; a0.w += xk * w0.w;
        a1.x += xk * w1.x; a1.y += xk * w1.y; a1.z += xk * w1.z; a1.w += xk * w1.w;
        a2.x += xk * w2.x; a2.y += xk * w2.y; a2.z += xk * w2.z; a2.w += xk * w2.w;
        a3.x += xk * w3.x; a3.y += xk * w3.y; a3.z += xk * w3.z; a3.w += xk * w3.w;
    }
    float4* yp = (float4*)(uout + (size_t)row * DD + g * 16);
    yp[0] = a0; yp[1] = a1; yp[2] = a2; yp[3] = a3;
}

__global__ void fuse_ego1(const float* __restrict__ embraw, const float* __restrict__ Wu,
                          const float* __restrict__ Wi, const float* __restrict__ alpha_p,
                          float* __restrict__ ego1) {
    __shared__ float4 Ws[2 * 64 * 16];
    int t = threadIdx.x;
    {
        const float4* Wv = (const float4*)Wu;
        const float4* Wv2 = (const float4*)Wi;
        for (int i = t; i < 1024; i += 256) {
            Ws[i] = Wv[i];
            Ws[1024 + i] = Wv2[i];
        }
    }
    __syncthreads();
    float alpha = alpha_p[0];
    int lane = t & 63;
    int g = t >> 6;
    int row = blockIdx.x * 64 + lane;
    if (row >= NADJ) return;
    const float4* Wb = (row < NUu) ? Ws : Ws + 1024;

    float xr[64];
    const float4* xp = (const float4*)(embraw + (size_t)row * DD);
#pragma unroll
    for (int i = 0; i < 16; ++i) {
        float4 v = xp[i];
        xr[4 * i + 0] = PRELU(v.x);
        xr[4 * i + 1] = PRELU(v.y);
        xr[4 * i + 2] = PRELU(v.z);
        xr[4 * i + 3] = PRELU(v.w);
    }
    float4 a0 = {0, 0, 0, 0}, a1 = a0, a2 = a0, a3 = a0;
#pragma unroll
    for (int k = 0; k < 64; ++k) {
        float xk = xr[k];
        const float4* wr = &Wb[k * 16 + g * 4];
        float4 w0 = wr[0], w1 = wr[1], w2 = wr[2], w3 = wr[3];
        a0.x += xk * w0.x; a0.y += xk * w0.y; a0.z += xk * w0.z; a0.w += xk * w0.w;
        a1.x += xk * w1.x; a1.y += xk * w1.y; a1.z += xk * w1.z; a1.w += xk * w1.w;
        a2.x += xk * w2.x; a2.y += xk * w2.y; a2.z += xk * w2.z; a2.w += xk * w2.w;
        a3.x += xk * w3.x; a3.y += xk * w3.y; a3.z += xk * w3.z; a3.w += xk * w3.w;
    }
    float4* yp = (float4*)(ego1 + (size_t)row * DD + g * 16);
    yp[0] = a0; yp[1] = a1; yp[2] = a2; yp[3] = a3;
}

// ============== outputs (users + items in one kernel) ==============
__global__ void out_combined(const float* __restrict__ embraw, const float* __restrict__ emb1raw,
                             const float* __restrict__ alpha_p, float* __restrict__ outp) {
    float alpha = alpha_p[0];
    int i = blockIdx.x * blockDim.x + threadIdx.x;
    if (i < NUu * DD) {
        int row = i >> 6, c = i & 63;
        float a = embraw[i];
        a = PRELU(a);
        float b = emb1raw[i];
        b = PRELU(b);
        outp[(size_t)row * 128 + c] = a;
        outp[(size_t)row * 128 + 64 + c] = b;
    } else {
        int i2 = i - NUu * DD;
        if (i2 >= NIi * DD) return;
        int row = i2 >> 6, c = i2 & 63;
        float s0 = 0.f, s1 = 0.f;
#pragma unroll
        for (int r = 0; r < RR; ++r) {
            size_t idx = ((size_t)NUu + (size_t)row * RR + r) * DD + c;
            float a = embraw[idx];
            s0 += PRELU(a);
            float b = emb1raw[idx];
            s1 += PRELU(b);
        }
        size_t obase = (size_t)NUu * 128 + (size_t)row * 128 + c;
        outp[obase] = s0 / 5.0f;
        outp[obase + 64] = s1 / 5.0f;
    }
}

// ============================ host ============================
extern "C" void kernel_launch(void* const* d_in, const int* in_sizes, int n_in,
                              void* d_out, int out_size, void* d_ws, size_t ws_size,
                              hipStream_t stream) {
    const float* user_emb  = (const float*)d_in[0];
    const float* item_emb  = (const float*)d_in[1];
    const float* w_r1_w    = (const float*)d_in[2];
    const float* w_r1_b    = (const float*)d_in[3];
    const float* social_w1 = (const float*)d_in[4];
    const float* user_w1   = (const float*)d_in[5];
    const float* item_w1   = (const float*)d_in[6];
    const float* alpha     = (const float*)d_in[7];
    const float* social_vals = (const float*)d_in[8];
    const float* adj_vals    = (const float*)d_in[9];
    const int* social_rows = (const int*)d_in[10];
    const int* social_cols = (const int*)d_in[11];
    const int* adj_rows    = (const int*)d_in[12];
    const int* adj_cols    = (const int*)d_in[13];
    float* out = (float*)d_out;

    float* A  = (float*)d_ws;              // part (during build) -> raw0 -> ego1
    float* B  = A + (size_t)NU5 * DD;      // t1 -> u
    float* C  = B + (size_t)NU5 * DD;      // raw1 -> emb1raw
    float* Dm = C + (size_t)NU5 * DD;      // embraw
    int*  s_ptr = (int*)(Dm + (size_t)NADJ * DD);
    int2* s_ecv = (int2*)(s_ptr + (NU5 + 2));
    int*  a_ptr = (int*)(s_ecv + NNZ_S);
    int2* a_ecv = (int2*)(a_ptr + (NADJ + 2));
    int*  gcur_s  = (int*)(a_ecv + NNZ_A);
    int*  gcur_a  = gcur_s + NBK;
    int*  gbase_s = gcur_a + NBK;
    int*  gbase_a = gbase_s + NBK;
    size_t need = (size_t)((char*)(gbase_a + NBK) - (char*)d_ws);
    int4* part = (int4*)A;  // aliases A: dead until first spmm writes raw0

    if (ws_size >= need) {
        // zero both gcur arrays in one tiny memset (contiguous)
        hipMemsetAsync(gcur_s, 0, 2 * NBK * sizeof(int), stream);
        // partition both matrices (bucket-contiguous writes into part; social first)
        partition_edges<10><<<(NNZ_S + CHUNK - 1) / CHUNK, 256, 0, stream>>>(
            social_rows, social_cols, social_vals, NNZ_S, gcur_s, part, CAP_S);
        // social: counting-sort fill can start only after its partition; do scan for
        // social together with adj after adj's partition (adj partition writes a
        // disjoint region of part? NO - same part buffer). So: finish social fully first.
        scan_buckets<<<2, 256, 0, stream>>>(gcur_s, gbase_s, s_ptr,
                                            gcur_a, gbase_a, a_ptr);  // adj half is zeros; rerun later
        bucket_sort_fill<10><<<NBUCK_S, 256, 0, stream>>>(
            part, gcur_s, gbase_s, CAP_S, NU5, s_ptr, s_ecv);
        // adj build (reuses part)
        partition_edges<9><<<(NNZ_A + CHUNK - 1) / CHUNK, 256, 0, stream>>>(
            adj_rows, adj_cols, adj_vals, NNZ_A, gcur_a, part, CAP_A);
        scan_buckets<<<2, 256, 0, stream>>>(gcur_s, gbase_s, s_ptr,
                                            gcur_a, gbase_a, a_ptr);
        bucket_sort_fill<9><<<NBUCK_A, 256, 0, stream>>>(
            part, gcur_a, gbase_a, CAP_A, NADJ, a_ptr, a_ecv);

        // ---- pipeline ----
        spmm_csr<false><<<(NU5 * 64 + 255) / 256, 256, 0, stream>>>(
            s_ptr, s_ecv, user_emb, nullptr, A, NU5);
        gemm64_prelu<<<(NU5 + 63) / 64, 256, 0, stream>>>(A, social_w1, alpha, B, NU5);
        spmm_csr<false><<<(NU5 * 64 + 255) / 256, 256, 0, stream>>>(
            s_ptr, s_ecv, B, nullptr, C, NU5);
        fuse_u<<<(NUu + 63) / 64, 256, 0, stream>>>(A, C, w_r1_w, w_r1_b, alpha, B);
        spmm_csr<true><<<(NADJ * 64 + 255) / 256, 256, 0, stream>>>(
            a_ptr, a_ecv, B, item_emb, Dm, NADJ);
        fuse_ego1<<<(NADJ + 63) / 64, 256, 0, stream>>>(Dm, user_w1, item_w1, alpha, A);
        spmm_csr<false><<<(NADJ * 64 + 255) / 256, 256, 0, stream>>>(
            a_ptr, a_ecv, A, nullptr, C, NADJ);
    } else {
        // ---- atomic fallback ----
        hipMemsetAsync(A, 0, (size_t)NU5 * DD * sizeof(float), stream);
        spmm_atomic<<<(NNZ_S * 16 + 255) / 256, 256, 0, stream>>>(
            social_rows, social_cols, social_vals, user_emb, A, NNZ_S);
        gemm64_prelu<<<(NU5 + 63) / 64, 256, 0, stream>>>(A, social_w1, alpha, B, NU5);
        hipMemsetAsync(C, 0, (size_t)NU5 * DD * sizeof(float), stream);
        spmm_atomic<<<(NNZ_S * 16 + 255) / 256, 256, 0, stream>>>(
            social_rows, social_cols, social_vals, B, C, NNZ_S);
        fuse_u<<<(NUu + 63) / 64, 256, 0, stream>>>(A, C, w_r1_w, w_r1_b, alpha, B);
        hipMemcpyAsync(B + (size_t)NUu * DD, item_emb, (size_t)NI5 * DD * sizeof(float),
                       hipMemcpyDeviceToDevice, stream);
        hipMemsetAsync(Dm, 0, (size_t)NADJ * DD * sizeof(float), stream);
        spmm_atomic<<<(NNZ_A * 16 + 255) / 256, 256, 0, stream>>>(
            adj_rows, adj_cols, adj_vals, B, Dm, NNZ_A);
        fuse_ego1<<<(NADJ + 63) / 64, 256, 0, stream>>>(Dm, user_w1, item_w1, alpha, A);
        hipMemsetAsync(C, 0, (size_t)NADJ * DD * sizeof(float), stream);
        spmm_atomic<<<(NNZ_A * 16 + 255) / 256, 256, 0, stream>>>(
            adj_rows, adj_cols, adj_vals, A, C, NNZ_A);
    }

    out_combined<<<((NUu + NIi) * DD + 255) / 256, 256, 0, stream>>>(Dm, C, alpha, out);
}